// Round 16
// baseline (288.205 us; speedup 1.0000x reference)
//
#include <hip/hip_runtime.h>

#define NNODES 100000
#define NEDGES 1600000
#define FIN 256
#define HID 128
#define NG 128
#define BSHIFT 7
#define BSZ 128
#define NB 782            // buckets of 128 nodes (dst>>7)
#define NW 1024           // histogram workgroups

static constexpr float BN_EPS_C = 1e-5f;

typedef __attribute__((ext_vector_type(8))) short bf16x8;
typedef __attribute__((ext_vector_type(4))) float f32x4;
typedef __attribute__((ext_vector_type(2))) float f32x2;

#if defined(__has_builtin)
#if __has_builtin(__builtin_amdgcn_cvt_pk_f32_fp8)
#define HAS_HWFP8 1
#endif
#endif

__device__ __forceinline__ float b2f(unsigned short u) {
    union { unsigned int i; float f; } c; c.i = ((unsigned int)u) << 16; return c.f;
}
__device__ __forceinline__ unsigned short f2b(float f) {
    union { float f; unsigned int i; } c; c.f = f;
    unsigned int u = c.i;
    u += 0x7fffu + ((u >> 16) & 1u);   // round-to-nearest-even
    return (unsigned short)(u >> 16);
}

// fp8 e4m3fn encode of PRE-SCALED value (caller multiplies by 64).
// Magnitude clamped to [2^-6, 448] so the stored value is always a normal.
__device__ __forceinline__ unsigned char f2e8(float f) {
    union { float f; unsigned int u; } c; c.f = f;
    unsigned int s = (c.u >> 24) & 0x80u;
    c.u &= 0x7fffffffu;
    c.f = fminf(fmaxf(c.f, 0.015625f), 448.f);
    unsigned int u = c.u + 0x7ffffu + ((c.u >> 20) & 1u);   // RNE to 3-bit mantissa
    int e = (int)(u >> 23) - 127;
    unsigned int m = (u >> 20) & 7u;
    return (unsigned char)(s | ((unsigned int)(e + 7) << 3) | m);
}

__device__ __forceinline__ float e8byte(unsigned int b) {
    union { unsigned int u; float f; } c;
    c.u = ((b & 0x80u) << 24) | (0x3C000000u + ((b & 0x7fu) << 20));
    return c.f;
}
__device__ __forceinline__ f32x2 e8plo(unsigned int w) {
#ifdef HAS_HWFP8
    return __builtin_amdgcn_cvt_pk_f32_fp8(w, false);
#else
    f32x2 r; r[0] = e8byte(w & 0xffu); r[1] = e8byte((w >> 8) & 0xffu); return r;
#endif
}
__device__ __forceinline__ f32x2 e8phi(unsigned int w) {
#ifdef HAS_HWFP8
    return __builtin_amdgcn_cvt_pk_f32_fp8(w, true);
#else
    f32x2 r; r[0] = e8byte((w >> 16) & 0xffu); r[1] = e8byte(w >> 24); return r;
#endif
}
__device__ __forceinline__ f32x2 bdec(unsigned int u) {
    union { unsigned int i[2]; f32x2 f; } c;
    c.i[0] = u << 16;
    c.i[1] = u & 0xffff0000u;
    return c.f;
}

// pass A: per-WG LDS histogram over 782 buckets
__global__ __launch_bounds__(256) void kbA(const int* __restrict__ dst, int* __restrict__ hist) {
    __shared__ int h[NB];
    int w = blockIdx.x, t = threadIdx.x;
    for (int i = t; i < NB; i += 256) h[i] = 0;
    __syncthreads();
    int beg = (int)((long long)w * NEDGES / NW);
    int end = (int)((long long)(w + 1) * NEDGES / NW);
    for (int i = beg + t; i < end; i += 256) atomicAdd(&h[dst[i] >> BSHIFT], 1);
    __syncthreads();
    for (int i = t; i < NB; i += 256) hist[i * NW + w] = h[i];
}

// pass B: per-bucket exclusive scan across NW=1024 WGs (4 per thread) + bucket totals
__global__ __launch_bounds__(256) void kbB2(const int* __restrict__ hist,
                                            int* __restrict__ off,
                                            int* __restrict__ btot) {
    __shared__ int s[256];
    int b = blockIdx.x, t = threadIdx.x;
    int base = b * NW + t * 4;
    int v0 = hist[base], v1 = hist[base + 1], v2 = hist[base + 2], v3 = hist[base + 3];
    int p1 = v0, p2 = v0 + v1, p3 = v0 + v1 + v2, tot = p3 + v3;
    s[t] = tot;
    __syncthreads();
    for (int o = 1; o < 256; o <<= 1) {
        int a = (t >= o) ? s[t - o] : 0;
        __syncthreads();
        s[t] += a;
        __syncthreads();
    }
    int ex = s[t] - tot;
    off[base] = ex; off[base + 1] = ex + p1; off[base + 2] = ex + p2; off[base + 3] = ex + p3;
    if (t == 255) btot[b] = s[255];
}

// bucket-base exclusive scan (one block, 1024 threads)
__global__ __launch_bounds__(1024) void kbT(const int* __restrict__ btot,
                                            int* __restrict__ bbase,
                                            int* __restrict__ rowptr) {
    __shared__ int s[1024];
    int t = threadIdx.x;
    int v = (t < NB) ? btot[t] : 0;
    s[t] = v;
    __syncthreads();
    for (int o = 1; o < 1024; o <<= 1) {
        int a = (t >= o) ? s[t - o] : 0;
        __syncthreads();
        s[t] += a;
        __syncthreads();
    }
    if (t < NB) bbase[t] = s[t] - v;
    if (t == NB - 1) { bbase[NB] = s[t]; rowptr[NNODES] = NEDGES; }
}

// pass C: scatter packed (src<<7 | dstLow) into bucket-contiguous regions
__global__ __launch_bounds__(256) void kbC2(const int* __restrict__ src,
                                            const int* __restrict__ dst,
                                            const int* __restrict__ off,
                                            const int* __restrict__ bbase,
                                            int* __restrict__ pairs) {
    __shared__ int cur[NB];
    int w = blockIdx.x, t = threadIdx.x;
    for (int i = t; i < NB; i += 256) cur[i] = off[i * NW + w] + bbase[i];
    __syncthreads();
    int beg = (int)((long long)w * NEDGES / NW);
    int end = (int)((long long)(w + 1) * NEDGES / NW);
    for (int i = beg + t; i < end; i += 256) {
        int d = dst[i];
        int pos = atomicAdd(&cur[d >> BSHIFT], 1);
        pairs[pos] = (src[i] << BSHIFT) | (d & (BSZ - 1));
    }
}

// per bucket: count per node (LDS), local scan -> rowptr/dis/selfn
__global__ __launch_bounds__(256) void kb2y(const int* __restrict__ bbase,
                                            const int* __restrict__ pairs,
                                            int* __restrict__ rowptr,
                                            float* __restrict__ dis,
                                            float* __restrict__ selfn) {
    int b = blockIdx.x;
    int nbase = b * BSZ;
    int nmax = NNODES - nbase; if (nmax > BSZ) nmax = BSZ;
    __shared__ int cnt[BSZ];
    __shared__ int cur[BSZ];
    int t = threadIdx.x;
    if (t < BSZ) cnt[t] = 0;
    __syncthreads();
    int beg = bbase[b], end = bbase[b + 1];
    for (int i = beg + t; i < end; i += 256) atomicAdd(&cnt[pairs[i] & (BSZ - 1)], 1);
    __syncthreads();
    if (t < BSZ) cur[t] = cnt[t];
    __syncthreads();
    for (int o = 1; o < BSZ; o <<= 1) {
        int a = (t >= o && t < BSZ) ? cur[t - o] : 0;
        __syncthreads();
        if (t < BSZ) cur[t] += a;
        __syncthreads();
    }
    if (t < nmax) {
        int v = cnt[t];
        rowptr[nbase + t] = cur[t] - v + beg;
        float d = 1.0f + (float)v;
        dis[nbase + t] = rsqrtf(d);
        selfn[nbase + t] = 1.0f / d;
    }
}

// per bucket: place pairs directly as packed edges (src<<15 | u15 weight)
__global__ __launch_bounds__(256) void kb2z(const int* __restrict__ bbase,
                                            const int* __restrict__ pairs,
                                            const int* __restrict__ rowptr,
                                            const float* __restrict__ dis,
                                            unsigned int* __restrict__ edgp) {
    int b = blockIdx.x;
    int nbase = b * BSZ;
    int nmax = NNODES - nbase; if (nmax > BSZ) nmax = BSZ;
    __shared__ int cur[BSZ];
    __shared__ float disl[BSZ];
    int t = threadIdx.x;
    if (t < nmax) {
        cur[t] = rowptr[nbase + t];
        disl[t] = dis[nbase + t];
    }
    __syncthreads();
    int beg = bbase[b], end = bbase[b + 1];
    for (int i = beg + t; i < end; i += 256) {
        int p = pairs[i];
        int s = p >> BSHIFT;
        float w = dis[s] * disl[p & (BSZ - 1)];
        unsigned int u = (unsigned int)(w * 32767.f + 0.5f);
        int pos = atomicAdd(&cur[p & (BSZ - 1)], 1);
        edgp[pos] = ((unsigned int)s << 15) | u;
    }
}

// Convert all three W matrices fp32 -> hi/lo bf16 in MFMA frag-major layout (one launch)
__global__ __launch_bounds__(256) void k_wconv3(const float* __restrict__ W1,
                                                const float* __restrict__ W2,
                                                const float* __restrict__ W3,
                                                unsigned short* __restrict__ whl1,
                                                unsigned short* __restrict__ whl2,
                                                unsigned short* __restrict__ whl3) {
    int idx = blockIdx.x * 256 + threadIdx.x;
    const float* W; unsigned short* whl;
    if (idx < FIN * 128) { W = W1; whl = whl1; }
    else if (idx < (FIN + HID) * 128) { W = W2; whl = whl2; idx -= FIN * 128; }
    else if (idx < (FIN + 2 * HID) * 128) { W = W3; whl = whl3; idx -= (FIN + HID) * 128; }
    else return;
    int k = idx >> 7, c = idx & 127;
    float v = W[k * 128 + c];
    unsigned short hi = f2b(v);
    unsigned short lo = f2b(v - b2f(hi));
    int kstep = k >> 5, kk = k & 31, g = kk >> 3, j = kk & 7;
    int tile = c >> 4, lane = (c & 15) + 16 * g;
    size_t b0 = ((((size_t)kstep * 2 + 0) * 8 + tile) * 64 + lane) * 8 + j;
    size_t b1 = ((((size_t)kstep * 2 + 1) * 8 + tile) * 64 + lane) * 8 + j;
    whl[b0] = hi;
    whl[b1] = lo;
}

// MFMA GEMM. MODE 0: A fp32, hi/lo split (3 MFMAs). MODE 1: A bf16 row-major (2 MFMAs).
// Epilogue: hwb = fp8x64 (OUT8) or bf16. (self-term/bias handled in gather)
template<int K, int MODE, int OUT8>
__global__ __launch_bounds__(256) void k_gemm_mfma(const void* __restrict__ Araw,
                                                   const unsigned short* __restrict__ whl,
                                                   void* __restrict__ hwbv) {
    __shared__ __align__(16) unsigned short Ah0[2048];
    __shared__ __align__(16) unsigned short Ah1[2048];
    __shared__ __align__(16) unsigned short Bs[8192];

    const int tid = threadIdx.x;
    const int w = tid >> 6;
    const int lane = tid & 63;
    const int m0 = blockIdx.x * 64;
    const int ar = tid >> 2;
    const int ak = (tid & 3) * 8;
    const int adst = (((ar >> 4) * 64) + (ar & 15) + 16 * (ak >> 3)) * 8;

    f32x4 acc[8] = {};

    for (int kt = 0; kt < K; kt += 32) {
        if (MODE == 0) {
            const float* A = (const float*)Araw;
            float4 v0 = {0.f,0.f,0.f,0.f}, v1 = {0.f,0.f,0.f,0.f};
            int grow = m0 + ar;
            if (grow < NNODES) {
                const float* s = A + (size_t)grow * K + kt + ak;
                v0 = *(const float4*)(s);
                v1 = *(const float4*)(s + 4);
            }
            float av[8];
            *(float4*)(av) = v0; *(float4*)(av + 4) = v1;
            bf16x8 hv, lv;
            #pragma unroll
            for (int j = 0; j < 8; ++j) {
                unsigned short h = f2b(av[j]);
                hv[j] = (short)h;
                lv[j] = (short)f2b(av[j] - b2f(h));
            }
            *(bf16x8*)&Ah0[adst] = hv;
            *(bf16x8*)&Ah1[adst] = lv;
        } else {
            const unsigned short* A = (const unsigned short*)Araw;
            bf16x8 hv = {};
            int grow = m0 + ar;
            if (grow < NNODES)
                hv = *(const bf16x8*)(A + (size_t)grow * K + kt + ak);
            *(bf16x8*)&Ah0[adst] = hv;
        }
        {
            const float4* bsrc = (const float4*)(whl + (size_t)(kt >> 5) * 8192);
            float4* bdst = (float4*)Bs;
            #pragma unroll
            for (int i = 0; i < 4; ++i) bdst[tid * 4 + i] = bsrc[tid * 4 + i];
        }
        __syncthreads();
        bf16x8 a0 = *(const bf16x8*)&Ah0[(w * 64 + lane) * 8];
        bf16x8 a1;
        if (MODE == 0) a1 = *(const bf16x8*)&Ah1[(w * 64 + lane) * 8];
        #pragma unroll
        for (int t = 0; t < 8; ++t) {
            bf16x8 b0 = *(const bf16x8*)&Bs[(t * 64 + lane) * 8];
            bf16x8 b1 = *(const bf16x8*)&Bs[4096 + (t * 64 + lane) * 8];
            acc[t] = __builtin_amdgcn_mfma_f32_16x16x32_bf16(a0, b0, acc[t], 0, 0, 0);
            acc[t] = __builtin_amdgcn_mfma_f32_16x16x32_bf16(a0, b1, acc[t], 0, 0, 0);
            if (MODE == 0)
                acc[t] = __builtin_amdgcn_mfma_f32_16x16x32_bf16(a1, b0, acc[t], 0, 0, 0);
        }
        __syncthreads();
    }

    const int colLo = lane & 15;
    const int gq = lane >> 4;
    #pragma unroll
    for (int i = 0; i < 4; ++i) {
        int row = m0 + w * 16 + gq * 4 + i;
        if (row < NNODES) {
            #pragma unroll
            for (int t = 0; t < 8; ++t) {
                int col = t * 16 + colLo;
                float v = acc[t][i];
                if (OUT8) {
                    ((unsigned char*)hwbv)[(size_t)row * HID + col] = f2e8(v * 64.f);
                } else {
                    ((unsigned short*)hwbv)[(size_t)row * HID + col] = f2b(v);
                }
            }
        }
    }
}

// SUBWAVE-PER-NODE gather: each 16-lane subwave owns one node (block = 16 nodes,
// grid = N/16). l4 covers feats 8*l4..8*l4+7. fp8: 8 edges/iter; bf16: 4 edges/iter.
// Self-term inline from hwb[node]*selfn + bias.
template<int IN8>
__global__ __launch_bounds__(256) void k_gather(const int* __restrict__ rowptr,
                                                const unsigned int* __restrict__ edgp,
                                                const void* __restrict__ hwbv,
                                                const float* __restrict__ selfn,
                                                const float* __restrict__ bias,
                                                unsigned short* __restrict__ agb) {
    const int lane = threadIdx.x & 63;
    const int sub = lane >> 4;
    const int l4 = lane & 15;
    const int node = blockIdx.x * 16 + ((threadIdx.x >> 6) << 2) + sub;
    int beg = rowptr[node], end = rowptr[node + 1];
    const float q = IN8 ? (1.0f / (32767.0f * 64.0f)) : (1.0f / 32767.0f);
    const unsigned char* hb = (const unsigned char*)hwbv;
    f32x2 a0 = {0.f,0.f}, a1 = {0.f,0.f}, a2 = {0.f,0.f}, a3 = {0.f,0.f};
    int e = beg;
    if (IN8) {
        for (; e + 7 < end; e += 8) {
            unsigned int p0 = edgp[e], p1 = edgp[e + 1];
            unsigned int p2 = edgp[e + 2], p3 = edgp[e + 3];
            unsigned int p4 = edgp[e + 4], p5 = edgp[e + 5];
            unsigned int p6 = edgp[e + 6], p7 = edgp[e + 7];
            uint2 v0 = *(const uint2*)(hb + (size_t)(p0 >> 15) * HID + l4 * 8);
            uint2 v1 = *(const uint2*)(hb + (size_t)(p1 >> 15) * HID + l4 * 8);
            uint2 v2 = *(const uint2*)(hb + (size_t)(p2 >> 15) * HID + l4 * 8);
            uint2 v3 = *(const uint2*)(hb + (size_t)(p3 >> 15) * HID + l4 * 8);
            uint2 v4 = *(const uint2*)(hb + (size_t)(p4 >> 15) * HID + l4 * 8);
            uint2 v5 = *(const uint2*)(hb + (size_t)(p5 >> 15) * HID + l4 * 8);
            uint2 v6 = *(const uint2*)(hb + (size_t)(p6 >> 15) * HID + l4 * 8);
            uint2 v7 = *(const uint2*)(hb + (size_t)(p7 >> 15) * HID + l4 * 8);
            float w0 = (float)(p0 & 0x7fffu) * q, w1 = (float)(p1 & 0x7fffu) * q;
            float w2 = (float)(p2 & 0x7fffu) * q, w3 = (float)(p3 & 0x7fffu) * q;
            float w4 = (float)(p4 & 0x7fffu) * q, w5 = (float)(p5 & 0x7fffu) * q;
            float w6 = (float)(p6 & 0x7fffu) * q, w7 = (float)(p7 & 0x7fffu) * q;
            f32x2 wa = {w0, w0}, wb = {w1, w1}, wc = {w2, w2}, wd = {w3, w3};
            f32x2 we = {w4, w4}, wf = {w5, w5}, wg = {w6, w6}, wh = {w7, w7};
            a0 += e8plo(v0.x) * wa; a1 += e8phi(v0.x) * wa;
            a2 += e8plo(v0.y) * wa; a3 += e8phi(v0.y) * wa;
            a0 += e8plo(v1.x) * wb; a1 += e8phi(v1.x) * wb;
            a2 += e8plo(v1.y) * wb; a3 += e8phi(v1.y) * wb;
            a0 += e8plo(v2.x) * wc; a1 += e8phi(v2.x) * wc;
            a2 += e8plo(v2.y) * wc; a3 += e8phi(v2.y) * wc;
            a0 += e8plo(v3.x) * wd; a1 += e8phi(v3.x) * wd;
            a2 += e8plo(v3.y) * wd; a3 += e8phi(v3.y) * wd;
            a0 += e8plo(v4.x) * we; a1 += e8phi(v4.x) * we;
            a2 += e8plo(v4.y) * we; a3 += e8phi(v4.y) * we;
            a0 += e8plo(v5.x) * wf; a1 += e8phi(v5.x) * wf;
            a2 += e8plo(v5.y) * wf; a3 += e8phi(v5.y) * wf;
            a0 += e8plo(v6.x) * wg; a1 += e8phi(v6.x) * wg;
            a2 += e8plo(v6.y) * wg; a3 += e8phi(v6.y) * wg;
            a0 += e8plo(v7.x) * wh; a1 += e8phi(v7.x) * wh;
            a2 += e8plo(v7.y) * wh; a3 += e8phi(v7.y) * wh;
        }
    } else {
        for (; e + 3 < end; e += 4) {
            unsigned int p0 = edgp[e], p1 = edgp[e + 1];
            unsigned int p2 = edgp[e + 2], p3 = edgp[e + 3];
            float w0 = (float)(p0 & 0x7fffu) * q;
            float w1 = (float)(p1 & 0x7fffu) * q;
            float w2 = (float)(p2 & 0x7fffu) * q;
            float w3 = (float)(p3 & 0x7fffu) * q;
            f32x2 wa = {w0, w0}, wb = {w1, w1}, wc = {w2, w2}, wd = {w3, w3};
            size_t r0 = (size_t)(p0 >> 15), r1 = (size_t)(p1 >> 15);
            size_t r2 = (size_t)(p2 >> 15), r3 = (size_t)(p3 >> 15);
            uint4 v0 = *(const uint4*)(hb + r0 * (HID * 2) + l4 * 16);
            uint4 v1 = *(const uint4*)(hb + r1 * (HID * 2) + l4 * 16);
            uint4 v2 = *(const uint4*)(hb + r2 * (HID * 2) + l4 * 16);
            uint4 v3 = *(const uint4*)(hb + r3 * (HID * 2) + l4 * 16);
            a0 += bdec(v0.x) * wa; a1 += bdec(v0.y) * wa;
            a2 += bdec(v0.z) * wa; a3 += bdec(v0.w) * wa;
            a0 += bdec(v1.x) * wb; a1 += bdec(v1.y) * wb;
            a2 += bdec(v1.z) * wb; a3 += bdec(v1.w) * wb;
            a0 += bdec(v2.x) * wc; a1 += bdec(v2.y) * wc;
            a2 += bdec(v2.z) * wc; a3 += bdec(v2.w) * wc;
            a0 += bdec(v3.x) * wd; a1 += bdec(v3.y) * wd;
            a2 += bdec(v3.z) * wd; a3 += bdec(v3.w) * wd;
        }
    }
    for (; e < end; ++e) {
        unsigned int p = edgp[e];
        float w = (float)(p & 0x7fffu) * q;
        f32x2 wa = {w, w};
        size_t r = (size_t)(p >> 15);
        if (IN8) {
            uint2 v = *(const uint2*)(hb + r * HID + l4 * 8);
            a0 += e8plo(v.x) * wa; a1 += e8phi(v.x) * wa;
            a2 += e8plo(v.y) * wa; a3 += e8phi(v.y) * wa;
        } else {
            uint4 v = *(const uint4*)(hb + r * (HID * 2) + l4 * 16);
            a0 += bdec(v.x) * wa; a1 += bdec(v.y) * wa;
            a2 += bdec(v.z) * wa; a3 += bdec(v.w) * wa;
        }
    }
    // self-term: hw[node] * selfn + bias, relu, store bf16
    float sn = selfn[node] * (IN8 ? (1.0f / 64.0f) : 1.0f);
    f32x2 sn2 = {sn, sn};
    f32x2 h0, h1, h2, h3;
    if (IN8) {
        uint2 v = *(const uint2*)(hb + (size_t)node * HID + l4 * 8);
        h0 = e8plo(v.x); h1 = e8phi(v.x); h2 = e8plo(v.y); h3 = e8phi(v.y);
    } else {
        uint4 v = *(const uint4*)(hb + (size_t)node * (HID * 2) + l4 * 16);
        h0 = bdec(v.x); h1 = bdec(v.y); h2 = bdec(v.z); h3 = bdec(v.w);
    }
    float4 bA = *(const float4*)&bias[l4 * 8];
    float4 bB = *(const float4*)&bias[l4 * 8 + 4];
    a0 += h0 * sn2; a1 += h1 * sn2; a2 += h2 * sn2; a3 += h3 * sn2;
    float r0 = fmaxf(a0[0] + bA.x, 0.f), r1 = fmaxf(a0[1] + bA.y, 0.f);
    float r2 = fmaxf(a1[0] + bA.z, 0.f), r3 = fmaxf(a1[1] + bA.w, 0.f);
    float r4 = fmaxf(a2[0] + bB.x, 0.f), r5 = fmaxf(a2[1] + bB.y, 0.f);
    float r6 = fmaxf(a3[0] + bB.z, 0.f), r7 = fmaxf(a3[1] + bB.w, 0.f);
    uint4 o;
    o.x = (unsigned int)f2b(r0) | ((unsigned int)f2b(r1) << 16);
    o.y = (unsigned int)f2b(r2) | ((unsigned int)f2b(r3) << 16);
    o.z = (unsigned int)f2b(r4) | ((unsigned int)f2b(r5) << 16);
    o.w = (unsigned int)f2b(r6) | ((unsigned int)f2b(r7) << 16);
    *(uint4*)(agb + (size_t)node * HID + l4 * 8) = o;
}

// fused pool + BN + head. One graph per block, 1024 threads.
__global__ __launch_bounds__(1024) void k_pool_bn_head(const unsigned short* __restrict__ h,
                                                       const int* __restrict__ batch,
                                                       const float* __restrict__ gamma,
                                                       const float* __restrict__ beta,
                                                       const float* __restrict__ mean,
                                                       const float* __restrict__ var,
                                                       const float* __restrict__ lw,
                                                       const float* __restrict__ lb,
                                                       float* __restrict__ xb,
                                                       float* __restrict__ out2) {
    int g = blockIdx.x;
    int tid = threadIdx.x;
    int fg = tid & 15;
    int r = tid >> 4;
    __shared__ int bounds[2];
    if (tid < 2) {
        int target = g + tid;
        int a = 0, b = NNODES;
        while (a < b) { int m = (a + b) >> 1; if (batch[m] < target) a = m + 1; else b = m; }
        bounds[tid] = a;
    }
    __syncthreads();
    int s1 = bounds[0], e1 = bounds[1];
    f32x2 acc[4] = {};
    for (int i = s1 + r; i < e1; i += 64) {
        uint4 v = *(const uint4*)(h + (size_t)i * HID + fg * 8);
        acc[0] += bdec(v.x); acc[1] += bdec(v.y); acc[2] += bdec(v.z); acc[3] += bdec(v.w);
    }
    __shared__ f32x2 red[64][16][4];   // 32KB
    #pragma unroll
    for (int j = 0; j < 4; ++j) red[r][fg][j] = acc[j];
    __syncthreads();
    for (int off = 32; off >= 1; off >>= 1) {
        if (r < off) {
            #pragma unroll
            for (int j = 0; j < 4; ++j) red[r][fg][j] += red[r + off][fg][j];
        }
        __syncthreads();
    }
    __shared__ float xbl[128];
    if (r == 0) {
        float cnt = (float)((e1 - s1) > 0 ? (e1 - s1) : 1);
        float inv = 1.0f / cnt;
        #pragma unroll
        for (int j = 0; j < 4; ++j) {
            #pragma unroll
            for (int k2 = 0; k2 < 2; ++k2) {
                int f = fg * 8 + j * 2 + k2;
                float pooled = red[0][fg][j][k2] * inv;
                float xbv = (pooled - mean[f]) * rsqrtf(var[f] + BN_EPS_C) * gamma[f] + beta[f];
                xb[g * HID + f] = xbv;
                xbl[f] = xbv;
            }
        }
    }
    __syncthreads();
    if (tid < 64) {
        float x0 = xbl[tid], x1 = xbl[tid + 64];
        float s0 = x0 * lw[tid * 2 + 0] + x1 * lw[(tid + 64) * 2 + 0];
        float s1h = x0 * lw[tid * 2 + 1] + x1 * lw[(tid + 64) * 2 + 1];
        #pragma unroll
        for (int o = 1; o < 64; o <<= 1) {
            s0 += __shfl_xor(s0, o);
            s1h += __shfl_xor(s1h, o);
        }
        if (tid == 0) {
            out2[g * 2 + 0] = fmaxf(s0 + lb[0], 0.f);
            out2[g * 2 + 1] = fmaxf(s1h + lb[1], 0.f);
        }
    }
}

extern "C" void kernel_launch(void* const* d_in, const int* in_sizes, int n_in,
                              void* d_out, int out_size, void* d_ws, size_t ws_size,
                              hipStream_t stream) {
    const float* x     = (const float*)d_in[0];
    const int*   ei    = (const int*)d_in[1];
    const int*   batch = (const int*)d_in[3];
    const float* W1 = (const float*)d_in[4];
    const float* b1 = (const float*)d_in[5];
    const float* W2 = (const float*)d_in[6];
    const float* b2 = (const float*)d_in[7];
    const float* W3 = (const float*)d_in[8];
    const float* b3 = (const float*)d_in[9];
    const float* gamma = (const float*)d_in[10];
    const float* beta  = (const float*)d_in[11];
    const float* mean  = (const float*)d_in[12];
    const float* var   = (const float*)d_in[13];
    const float* lw = (const float*)d_in[14];
    const float* lb = (const float*)d_in[15];
    float* out = (float*)d_out;

    char* p = (char*)d_ws;
    unsigned short* HWB = (unsigned short*)p;          p += (size_t)NNODES * HID * 2;  // 25.6MB (fp8 uses half)
    unsigned short* AGB = (unsigned short*)p;          p += (size_t)NNODES * HID * 2;  // 25.6MB
    float* DIS    = (float*)p;                         p += (size_t)NNODES * 4;
    float* SELFN  = (float*)p;                         p += (size_t)NNODES * 4;
    int*   ROWPTR = (int*)p;                           p += (size_t)(NNODES + 64) * 4;
    unsigned int* EDGP = (unsigned int*)p;             p += (size_t)NEDGES * 4;
    int*   BTOT   = (int*)p;                           p += 1024 * 4;
    int*   BBASE  = (int*)p;                           p += 1024 * 4;
    unsigned short* WHL1 = (unsigned short*)p;         p += (size_t)FIN * 128 * 2 * 2;
    unsigned short* WHL2 = (unsigned short*)p;         p += (size_t)HID * 128 * 2 * 2;
    unsigned short* WHL3 = (unsigned short*)p;
    // build-phase aliases (consumed before gemm1/gather1 write HWB/AGB)
    int*   PAIRS  = (int*)HWB;                         // E i (6.4MB <= 25.6MB)
    int*   HIST   = (int*)AGB;                         // NB*NW i (3.2MB)
    int*   OFF    = HIST + NB * NW;                    // NB*NW i (3.2MB)

    const int* srcv = ei;
    const int* dstv = ei + NEDGES;

    // ---- CSR build (histogram -> scans -> scatter -> count -> place-as-EDGP) ----
    kbA<<<NW, 256, 0, stream>>>(dstv, HIST);
    kbB2<<<NB, 256, 0, stream>>>(HIST, OFF, BTOT);
    kbT<<<1, 1024, 0, stream>>>(BTOT, BBASE, ROWPTR);
    kbC2<<<NW, 256, 0, stream>>>(srcv, dstv, OFF, BBASE, PAIRS);
    kb2y<<<NB, 256, 0, stream>>>(BBASE, PAIRS, ROWPTR, DIS, SELFN);
    kb2z<<<NB, 256, 0, stream>>>(BBASE, PAIRS, ROWPTR, DIS, EDGP);
    // ---- W pre-conversion (all three, one launch) ----
    k_wconv3<<<((FIN + 2 * HID) * 128 + 255) / 256, 256, 0, stream>>>(W1, W2, W3, WHL1, WHL2, WHL3);

    dim3 gg((NNODES + 63) / 64);
    const int ggat = NNODES / 16;   // 6250, exact

    // layer 1 (A = fp32 x; hwb fp8 -- error damped through 2 more layers)
    k_gemm_mfma<FIN, 0, 1><<<gg, 256, 0, stream>>>(x, WHL1, HWB);
    k_gather<1><<<ggat, 256, 0, stream>>>(ROWPTR, EDGP, HWB, SELFN, b1, AGB);
    // layer 2 (A = relu'd bf16 AGB; hwb fp8)
    k_gemm_mfma<HID, 1, 1><<<gg, 256, 0, stream>>>(AGB, WHL2, HWB);
    k_gather<1><<<ggat, 256, 0, stream>>>(ROWPTR, EDGP, HWB, SELFN, b2, AGB);
    // layer 3 (hwb bf16 -- last layer's quantization is undamped, keep precise)
    k_gemm_mfma<HID, 1, 0><<<gg, 256, 0, stream>>>(AGB, WHL3, HWB);
    k_gather<0><<<ggat, 256, 0, stream>>>(ROWPTR, EDGP, HWB, SELFN, b3, AGB);

    // fused pool + BN + head
    k_pool_bn_head<<<NG, 1024, 0, stream>>>(AGB, batch, gamma, beta, mean, var,
                                            lw, lb, out, out + (size_t)NG * HID);
}

// Round 17
// 261.181 us; speedup vs baseline: 1.1035x; 1.1035x over previous
//
#include <hip/hip_runtime.h>

#define NNODES 100000
#define NEDGES 1600000
#define FIN 256
#define HID 128
#define NG 128
#define NB 391            // buckets of 256 nodes (dst>>8)
#define NW 256            // histogram workgroups
#define EPW 6250          // NEDGES / NW
#define GEMM_BLKS 1563    // ceil(NNODES/64)

static constexpr float BN_EPS_C = 1e-5f;

typedef __attribute__((ext_vector_type(8))) short bf16x8;
typedef __attribute__((ext_vector_type(4))) float f32x4;
typedef __attribute__((ext_vector_type(2))) float f32x2;

#if defined(__has_builtin)
#if __has_builtin(__builtin_amdgcn_cvt_pk_f32_fp8)
#define HAS_HWFP8 1
#endif
#endif

__device__ __forceinline__ float b2f(unsigned short u) {
    union { unsigned int i; float f; } c; c.i = ((unsigned int)u) << 16; return c.f;
}
__device__ __forceinline__ unsigned short f2b(float f) {
    union { float f; unsigned int i; } c; c.f = f;
    unsigned int u = c.i;
    u += 0x7fffu + ((u >> 16) & 1u);   // round-to-nearest-even
    return (unsigned short)(u >> 16);
}

// fp8 e4m3fn encode of PRE-SCALED value (caller multiplies by 64).
__device__ __forceinline__ unsigned char f2e8(float f) {
    union { float f; unsigned int u; } c; c.f = f;
    unsigned int s = (c.u >> 24) & 0x80u;
    c.u &= 0x7fffffffu;
    c.f = fminf(fmaxf(c.f, 0.015625f), 448.f);
    unsigned int u = c.u + 0x7ffffu + ((c.u >> 20) & 1u);   // RNE to 3-bit mantissa
    int e = (int)(u >> 23) - 127;
    unsigned int m = (u >> 20) & 7u;
    return (unsigned char)(s | ((unsigned int)(e + 7) << 3) | m);
}

__device__ __forceinline__ float e8byte(unsigned int b) {
    union { unsigned int u; float f; } c;
    c.u = ((b & 0x80u) << 24) | (0x3C000000u + ((b & 0x7fu) << 20));
    return c.f;
}
__device__ __forceinline__ f32x2 e8plo(unsigned int w) {
#ifdef HAS_HWFP8
    return __builtin_amdgcn_cvt_pk_f32_fp8(w, false);
#else
    f32x2 r; r[0] = e8byte(w & 0xffu); r[1] = e8byte((w >> 8) & 0xffu); return r;
#endif
}
__device__ __forceinline__ f32x2 e8phi(unsigned int w) {
#ifdef HAS_HWFP8
    return __builtin_amdgcn_cvt_pk_f32_fp8(w, true);
#else
    f32x2 r; r[0] = e8byte((w >> 16) & 0xffu); r[1] = e8byte(w >> 24); return r;
#endif
}
__device__ __forceinline__ f32x2 bdec(unsigned int u) {
    union { unsigned int i[2]; f32x2 f; } c;
    c.i[0] = u << 16;
    c.i[1] = u & 0xffff0000u;
    return c.f;
}

// ---- shared GEMM body (MFMA split-bf16). MODE 0: A fp32 hi/lo (3 MFMAs);
// MODE 1: A bf16 (2 MFMAs). OUT8: hwb = fp8 x64, else bf16. ----
template<int K, int MODE, int OUT8>
__device__ __forceinline__ void gemm_body(int blk,
                                          const void* __restrict__ Araw,
                                          const unsigned short* __restrict__ whl,
                                          void* __restrict__ hwbv) {
    __shared__ __align__(16) unsigned short Ah0[2048];
    __shared__ __align__(16) unsigned short Ah1[2048];
    __shared__ __align__(16) unsigned short Bs[8192];

    const int tid = threadIdx.x;
    const int w = tid >> 6;
    const int lane = tid & 63;
    const int m0 = blk * 64;
    const int ar = tid >> 2;
    const int ak = (tid & 3) * 8;
    const int adst = (((ar >> 4) * 64) + (ar & 15) + 16 * (ak >> 3)) * 8;

    f32x4 acc[8] = {};

    for (int kt = 0; kt < K; kt += 32) {
        if (MODE == 0) {
            const float* A = (const float*)Araw;
            float4 v0 = {0.f,0.f,0.f,0.f}, v1 = {0.f,0.f,0.f,0.f};
            int grow = m0 + ar;
            if (grow < NNODES) {
                const float* s = A + (size_t)grow * K + kt + ak;
                v0 = *(const float4*)(s);
                v1 = *(const float4*)(s + 4);
            }
            float av[8];
            *(float4*)(av) = v0; *(float4*)(av + 4) = v1;
            bf16x8 hv, lv;
            #pragma unroll
            for (int j = 0; j < 8; ++j) {
                unsigned short h = f2b(av[j]);
                hv[j] = (short)h;
                lv[j] = (short)f2b(av[j] - b2f(h));
            }
            *(bf16x8*)&Ah0[adst] = hv;
            *(bf16x8*)&Ah1[adst] = lv;
        } else {
            const unsigned short* A = (const unsigned short*)Araw;
            bf16x8 hv = {};
            int grow = m0 + ar;
            if (grow < NNODES)
                hv = *(const bf16x8*)(A + (size_t)grow * K + kt + ak);
            *(bf16x8*)&Ah0[adst] = hv;
        }
        {
            const float4* bsrc = (const float4*)(whl + (size_t)(kt >> 5) * 8192);
            float4* bdst = (float4*)Bs;
            #pragma unroll
            for (int i = 0; i < 4; ++i) bdst[tid * 4 + i] = bsrc[tid * 4 + i];
        }
        __syncthreads();
        bf16x8 a0 = *(const bf16x8*)&Ah0[(w * 64 + lane) * 8];
        bf16x8 a1;
        if (MODE == 0) a1 = *(const bf16x8*)&Ah1[(w * 64 + lane) * 8];
        #pragma unroll
        for (int t = 0; t < 8; ++t) {
            bf16x8 b0 = *(const bf16x8*)&Bs[(t * 64 + lane) * 8];
            bf16x8 b1 = *(const bf16x8*)&Bs[4096 + (t * 64 + lane) * 8];
            acc[t] = __builtin_amdgcn_mfma_f32_16x16x32_bf16(a0, b0, acc[t], 0, 0, 0);
            acc[t] = __builtin_amdgcn_mfma_f32_16x16x32_bf16(a0, b1, acc[t], 0, 0, 0);
            if (MODE == 0)
                acc[t] = __builtin_amdgcn_mfma_f32_16x16x32_bf16(a1, b0, acc[t], 0, 0, 0);
        }
        __syncthreads();
    }

    const int colLo = lane & 15;
    const int gq = lane >> 4;
    #pragma unroll
    for (int i = 0; i < 4; ++i) {
        int row = m0 + w * 16 + gq * 4 + i;
        if (row < NNODES) {
            #pragma unroll
            for (int t = 0; t < 8; ++t) {
                int col = t * 16 + colLo;
                float v = acc[t][i];
                if (OUT8) {
                    ((unsigned char*)hwbv)[(size_t)row * HID + col] = f2e8(v * 64.f);
                } else {
                    ((unsigned short*)hwbv)[(size_t)row * HID + col] = f2b(v);
                }
            }
        }
    }
}

// FUSED: wconv3 (blocks 0..255) || kbA histogram (blocks 256..511)
__global__ __launch_bounds__(256) void k_prep(const float* __restrict__ W1,
                                              const float* __restrict__ W2,
                                              const float* __restrict__ W3,
                                              unsigned short* __restrict__ whl1,
                                              unsigned short* __restrict__ whl2,
                                              unsigned short* __restrict__ whl3,
                                              const int* __restrict__ dst,
                                              int* __restrict__ hist) {
    if (blockIdx.x < 256) {
        int idx = blockIdx.x * 256 + threadIdx.x;
        const float* W; unsigned short* whl;
        if (idx < FIN * 128) { W = W1; whl = whl1; }
        else if (idx < (FIN + HID) * 128) { W = W2; whl = whl2; idx -= FIN * 128; }
        else { W = W3; whl = whl3; idx -= (FIN + HID) * 128; }
        int k = idx >> 7, c = idx & 127;
        float v = W[k * 128 + c];
        unsigned short hi = f2b(v);
        unsigned short lo = f2b(v - b2f(hi));
        int kstep = k >> 5, kk = k & 31, g = kk >> 3, j = kk & 7;
        int tile = c >> 4, lane = (c & 15) + 16 * g;
        size_t b0 = ((((size_t)kstep * 2 + 0) * 8 + tile) * 64 + lane) * 8 + j;
        size_t b1 = ((((size_t)kstep * 2 + 1) * 8 + tile) * 64 + lane) * 8 + j;
        whl[b0] = hi;
        whl[b1] = lo;
    } else {
        __shared__ int h[NB];
        int w = blockIdx.x - 256, t = threadIdx.x;
        for (int i = t; i < NB; i += 256) h[i] = 0;
        __syncthreads();
        int base = w * EPW;
        for (int i = t; i < EPW; i += 256) atomicAdd(&h[dst[base + i] >> 8], 1);
        __syncthreads();
        for (int i = t; i < NB; i += 256) hist[i * NW + w] = h[i];
    }
}

// pass B: per-bucket exclusive scan across WGs (relative) + bucket totals
__global__ __launch_bounds__(256) void kbB2(const int* __restrict__ hist,
                                            int* __restrict__ off,
                                            int* __restrict__ btot) {
    __shared__ int s[NW];
    int b = blockIdx.x, t = threadIdx.x;
    int v = hist[b * NW + t];
    s[t] = v;
    __syncthreads();
    for (int o = 1; o < NW; o <<= 1) {
        int a = (t >= o) ? s[t - o] : 0;
        __syncthreads();
        s[t] += a;
        __syncthreads();
    }
    off[b * NW + t] = s[t] - v;
    if (t == NW - 1) btot[b] = s[t];
}

// bucket-base exclusive scan (one block)
__global__ __launch_bounds__(512) void kbT(const int* __restrict__ btot,
                                           int* __restrict__ bbase,
                                           int* __restrict__ rowptr) {
    __shared__ int s[512];
    int t = threadIdx.x;
    int v = (t < NB) ? btot[t] : 0;
    s[t] = v;
    __syncthreads();
    for (int o = 1; o < 512; o <<= 1) {
        int a = (t >= o) ? s[t - o] : 0;
        __syncthreads();
        s[t] += a;
        __syncthreads();
    }
    if (t < NB) bbase[t] = s[t] - v;
    if (t == NB - 1) { bbase[NB] = s[t]; rowptr[NNODES] = NEDGES; }
}

// FUSED: kbC2 scatter (blocks 0..255) || gemm1 <FIN,0,1> (blocks 256..1818)
__global__ __launch_bounds__(256) void k_c2g1(const int* __restrict__ src,
                                              const int* __restrict__ dst,
                                              const int* __restrict__ off,
                                              const int* __restrict__ bbase,
                                              int* __restrict__ pairs,
                                              const float* __restrict__ x,
                                              const unsigned short* __restrict__ whl1,
                                              void* __restrict__ hwbv) {
    if (blockIdx.x < 256) {
        __shared__ int cur[NB];
        int w = blockIdx.x, t = threadIdx.x;
        for (int i = t; i < NB; i += 256) cur[i] = off[i * NW + w] + bbase[i];
        __syncthreads();
        int base = w * EPW;
        for (int i = t; i < EPW; i += 256) {
            int d = dst[base + i];
            int pos = atomicAdd(&cur[d >> 8], 1);
            pairs[pos] = (src[base + i] << 8) | (d & 255);
        }
    } else {
        gemm_body<FIN, 0, 1>(blockIdx.x - 256, x, whl1, hwbv);
    }
}

// per bucket: count per node (LDS), local scan -> rowptr/dis/selfn
__global__ __launch_bounds__(256) void kb2y(const int* __restrict__ bbase,
                                            const int* __restrict__ pairs,
                                            int* __restrict__ rowptr,
                                            float* __restrict__ dis,
                                            float* __restrict__ selfn) {
    int b = blockIdx.x;
    int nbase = b * 256;
    int nmax = NNODES - nbase; if (nmax > 256) nmax = 256;
    __shared__ int cnt[256];
    __shared__ int cur[256];
    int t = threadIdx.x;
    cnt[t] = 0;
    __syncthreads();
    int beg = bbase[b], end = bbase[b + 1];
    for (int i = beg + t; i < end; i += 256) atomicAdd(&cnt[pairs[i] & 255], 1);
    __syncthreads();
    int v = cnt[t];
    cur[t] = v;
    __syncthreads();
    for (int o = 1; o < 256; o <<= 1) {
        int a = (t >= o) ? cur[t - o] : 0;
        __syncthreads();
        cur[t] += a;
        __syncthreads();
    }
    if (t < nmax) {
        rowptr[nbase + t] = cur[t] - v + beg;
        float d = 1.0f + (float)v;
        dis[nbase + t] = rsqrtf(d);
        selfn[nbase + t] = 1.0f / d;
    }
}

// per bucket: place pairs directly as packed edges (src<<15 | u15 weight)
__global__ __launch_bounds__(256) void kb2z(const int* __restrict__ bbase,
                                            const int* __restrict__ pairs,
                                            const int* __restrict__ rowptr,
                                            const float* __restrict__ dis,
                                            unsigned int* __restrict__ edgp) {
    int b = blockIdx.x;
    int nbase = b * 256;
    int nmax = NNODES - nbase; if (nmax > 256) nmax = 256;
    __shared__ int cur[256];
    __shared__ float disl[256];
    int t = threadIdx.x;
    if (t < nmax) {
        cur[t] = rowptr[nbase + t];
        disl[t] = dis[nbase + t];
    }
    __syncthreads();
    int beg = bbase[b], end = bbase[b + 1];
    for (int i = beg + t; i < end; i += 256) {
        int p = pairs[i];
        int s = p >> 8;
        float w = dis[s] * disl[p & 255];
        unsigned int u = (unsigned int)(w * 32767.f + 0.5f);
        int pos = atomicAdd(&cur[p & 255], 1);
        edgp[pos] = ((unsigned int)s << 15) | u;
    }
}

// standalone GEMM for layers 2/3
template<int K, int MODE, int OUT8>
__global__ __launch_bounds__(256) void k_gemm_mfma(const void* __restrict__ Araw,
                                                   const unsigned short* __restrict__ whl,
                                                   void* __restrict__ hwbv) {
    gemm_body<K, MODE, OUT8>(blockIdx.x, Araw, whl, hwbv);
}

// SUBWAVE-PER-NODE gather: 16-lane subwave owns one node. fp8: 8 edges/iter;
// bf16: 4 edges/iter. Self-term inline from hwb[node]*selfn + bias.
template<int IN8>
__global__ __launch_bounds__(256) void k_gather(const int* __restrict__ rowptr,
                                                const unsigned int* __restrict__ edgp,
                                                const void* __restrict__ hwbv,
                                                const float* __restrict__ selfn,
                                                const float* __restrict__ bias,
                                                unsigned short* __restrict__ agb) {
    const int lane = threadIdx.x & 63;
    const int sub = lane >> 4;
    const int l4 = lane & 15;
    const int node = blockIdx.x * 16 + ((threadIdx.x >> 6) << 2) + sub;
    int beg = rowptr[node], end = rowptr[node + 1];
    const float q = IN8 ? (1.0f / (32767.0f * 64.0f)) : (1.0f / 32767.0f);
    const unsigned char* hb = (const unsigned char*)hwbv;
    f32x2 a0 = {0.f,0.f}, a1 = {0.f,0.f}, a2 = {0.f,0.f}, a3 = {0.f,0.f};
    int e = beg;
    if (IN8) {
        for (; e + 7 < end; e += 8) {
            unsigned int p0 = edgp[e], p1 = edgp[e + 1];
            unsigned int p2 = edgp[e + 2], p3 = edgp[e + 3];
            unsigned int p4 = edgp[e + 4], p5 = edgp[e + 5];
            unsigned int p6 = edgp[e + 6], p7 = edgp[e + 7];
            uint2 v0 = *(const uint2*)(hb + (size_t)(p0 >> 15) * HID + l4 * 8);
            uint2 v1 = *(const uint2*)(hb + (size_t)(p1 >> 15) * HID + l4 * 8);
            uint2 v2 = *(const uint2*)(hb + (size_t)(p2 >> 15) * HID + l4 * 8);
            uint2 v3 = *(const uint2*)(hb + (size_t)(p3 >> 15) * HID + l4 * 8);
            uint2 v4 = *(const uint2*)(hb + (size_t)(p4 >> 15) * HID + l4 * 8);
            uint2 v5 = *(const uint2*)(hb + (size_t)(p5 >> 15) * HID + l4 * 8);
            uint2 v6 = *(const uint2*)(hb + (size_t)(p6 >> 15) * HID + l4 * 8);
            uint2 v7 = *(const uint2*)(hb + (size_t)(p7 >> 15) * HID + l4 * 8);
            float w0 = (float)(p0 & 0x7fffu) * q, w1 = (float)(p1 & 0x7fffu) * q;
            float w2 = (float)(p2 & 0x7fffu) * q, w3 = (float)(p3 & 0x7fffu) * q;
            float w4 = (float)(p4 & 0x7fffu) * q, w5 = (float)(p5 & 0x7fffu) * q;
            float w6 = (float)(p6 & 0x7fffu) * q, w7 = (float)(p7 & 0x7fffu) * q;
            f32x2 wa = {w0, w0}, wb = {w1, w1}, wc = {w2, w2}, wd = {w3, w3};
            f32x2 we = {w4, w4}, wf = {w5, w5}, wg = {w6, w6}, wh = {w7, w7};
            a0 += e8plo(v0.x) * wa; a1 += e8phi(v0.x) * wa;
            a2 += e8plo(v0.y) * wa; a3 += e8phi(v0.y) * wa;
            a0 += e8plo(v1.x) * wb; a1 += e8phi(v1.x) * wb;
            a2 += e8plo(v1.y) * wb; a3 += e8phi(v1.y) * wb;
            a0 += e8plo(v2.x) * wc; a1 += e8phi(v2.x) * wc;
            a2 += e8plo(v2.y) * wc; a3 += e8phi(v2.y) * wc;
            a0 += e8plo(v3.x) * wd; a1 += e8phi(v3.x) * wd;
            a2 += e8plo(v3.y) * wd; a3 += e8phi(v3.y) * wd;
            a0 += e8plo(v4.x) * we; a1 += e8phi(v4.x) * we;
            a2 += e8plo(v4.y) * we; a3 += e8phi(v4.y) * we;
            a0 += e8plo(v5.x) * wf; a1 += e8phi(v5.x) * wf;
            a2 += e8plo(v5.y) * wf; a3 += e8phi(v5.y) * wf;
            a0 += e8plo(v6.x) * wg; a1 += e8phi(v6.x) * wg;
            a2 += e8plo(v6.y) * wg; a3 += e8phi(v6.y) * wg;
            a0 += e8plo(v7.x) * wh; a1 += e8phi(v7.x) * wh;
            a2 += e8plo(v7.y) * wh; a3 += e8phi(v7.y) * wh;
        }
    } else {
        for (; e + 3 < end; e += 4) {
            unsigned int p0 = edgp[e], p1 = edgp[e + 1];
            unsigned int p2 = edgp[e + 2], p3 = edgp[e + 3];
            float w0 = (float)(p0 & 0x7fffu) * q;
            float w1 = (float)(p1 & 0x7fffu) * q;
            float w2 = (float)(p2 & 0x7fffu) * q;
            float w3 = (float)(p3 & 0x7fffu) * q;
            f32x2 wa = {w0, w0}, wb = {w1, w1}, wc = {w2, w2}, wd = {w3, w3};
            size_t r0 = (size_t)(p0 >> 15), r1 = (size_t)(p1 >> 15);
            size_t r2 = (size_t)(p2 >> 15), r3 = (size_t)(p3 >> 15);
            uint4 v0 = *(const uint4*)(hb + r0 * (HID * 2) + l4 * 16);
            uint4 v1 = *(const uint4*)(hb + r1 * (HID * 2) + l4 * 16);
            uint4 v2 = *(const uint4*)(hb + r2 * (HID * 2) + l4 * 16);
            uint4 v3 = *(const uint4*)(hb + r3 * (HID * 2) + l4 * 16);
            a0 += bdec(v0.x) * wa; a1 += bdec(v0.y) * wa;
            a2 += bdec(v0.z) * wa; a3 += bdec(v0.w) * wa;
            a0 += bdec(v1.x) * wb; a1 += bdec(v1.y) * wb;
            a2 += bdec(v1.z) * wb; a3 += bdec(v1.w) * wb;
            a0 += bdec(v2.x) * wc; a1 += bdec(v2.y) * wc;
            a2 += bdec(v2.z) * wc; a3 += bdec(v2.w) * wc;
            a0 += bdec(v3.x) * wd; a1 += bdec(v3.y) * wd;
            a2 += bdec(v3.z) * wd; a3 += bdec(v3.w) * wd;
        }
    }
    for (; e < end; ++e) {
        unsigned int p = edgp[e];
        float w = (float)(p & 0x7fffu) * q;
        f32x2 wa = {w, w};
        size_t r = (size_t)(p >> 15);
        if (IN8) {
            uint2 v = *(const uint2*)(hb + r * HID + l4 * 8);
            a0 += e8plo(v.x) * wa; a1 += e8phi(v.x) * wa;
            a2 += e8plo(v.y) * wa; a3 += e8phi(v.y) * wa;
        } else {
            uint4 v = *(const uint4*)(hb + r * (HID * 2) + l4 * 16);
            a0 += bdec(v.x) * wa; a1 += bdec(v.y) * wa;
            a2 += bdec(v.z) * wa; a3 += bdec(v.w) * wa;
        }
    }
    // self-term: hw[node] * selfn + bias, relu, store bf16
    float sn = selfn[node] * (IN8 ? (1.0f / 64.0f) : 1.0f);
    f32x2 sn2 = {sn, sn};
    f32x2 h0, h1, h2, h3;
    if (IN8) {
        uint2 v = *(const uint2*)(hb + (size_t)node * HID + l4 * 8);
        h0 = e8plo(v.x); h1 = e8phi(v.x); h2 = e8plo(v.y); h3 = e8phi(v.y);
    } else {
        uint4 v = *(const uint4*)(hb + (size_t)node * (HID * 2) + l4 * 16);
        h0 = bdec(v.x); h1 = bdec(v.y); h2 = bdec(v.z); h3 = bdec(v.w);
    }
    float4 bA = *(const float4*)&bias[l4 * 8];
    float4 bB = *(const float4*)&bias[l4 * 8 + 4];
    a0 += h0 * sn2; a1 += h1 * sn2; a2 += h2 * sn2; a3 += h3 * sn2;
    float r0 = fmaxf(a0[0] + bA.x, 0.f), r1 = fmaxf(a0[1] + bA.y, 0.f);
    float r2 = fmaxf(a1[0] + bA.z, 0.f), r3 = fmaxf(a1[1] + bA.w, 0.f);
    float r4 = fmaxf(a2[0] + bB.x, 0.f), r5 = fmaxf(a2[1] + bB.y, 0.f);
    float r6 = fmaxf(a3[0] + bB.z, 0.f), r7 = fmaxf(a3[1] + bB.w, 0.f);
    uint4 o;
    o.x = (unsigned int)f2b(r0) | ((unsigned int)f2b(r1) << 16);
    o.y = (unsigned int)f2b(r2) | ((unsigned int)f2b(r3) << 16);
    o.z = (unsigned int)f2b(r4) | ((unsigned int)f2b(r5) << 16);
    o.w = (unsigned int)f2b(r6) | ((unsigned int)f2b(r7) << 16);
    *(uint4*)(agb + (size_t)node * HID + l4 * 8) = o;
}

// fused pool + BN + head. One graph per block, 1024 threads.
__global__ __launch_bounds__(1024) void k_pool_bn_head(const unsigned short* __restrict__ h,
                                                       const int* __restrict__ batch,
                                                       const float* __restrict__ gamma,
                                                       const float* __restrict__ beta,
                                                       const float* __restrict__ mean,
                                                       const float* __restrict__ var,
                                                       const float* __restrict__ lw,
                                                       const float* __restrict__ lb,
                                                       float* __restrict__ xb,
                                                       float* __restrict__ out2) {
    int g = blockIdx.x;
    int tid = threadIdx.x;
    int fg = tid & 15;
    int r = tid >> 4;
    __shared__ int bounds[2];
    if (tid < 2) {
        int target = g + tid;
        int a = 0, b = NNODES;
        while (a < b) { int m = (a + b) >> 1; if (batch[m] < target) a = m + 1; else b = m; }
        bounds[tid] = a;
    }
    __syncthreads();
    int s1 = bounds[0], e1 = bounds[1];
    f32x2 acc[4] = {};
    for (int i = s1 + r; i < e1; i += 64) {
        uint4 v = *(const uint4*)(h + (size_t)i * HID + fg * 8);
        acc[0] += bdec(v.x); acc[1] += bdec(v.y); acc[2] += bdec(v.z); acc[3] += bdec(v.w);
    }
    __shared__ f32x2 red[64][16][4];   // 32KB
    #pragma unroll
    for (int j = 0; j < 4; ++j) red[r][fg][j] = acc[j];
    __syncthreads();
    for (int off = 32; off >= 1; off >>= 1) {
        if (r < off) {
            #pragma unroll
            for (int j = 0; j < 4; ++j) red[r][fg][j] += red[r + off][fg][j];
        }
        __syncthreads();
    }
    __shared__ float xbl[128];
    if (r == 0) {
        float cnt = (float)((e1 - s1) > 0 ? (e1 - s1) : 1);
        float inv = 1.0f / cnt;
        #pragma unroll
        for (int j = 0; j < 4; ++j) {
            #pragma unroll
            for (int k2 = 0; k2 < 2; ++k2) {
                int f = fg * 8 + j * 2 + k2;
                float pooled = red[0][fg][j][k2] * inv;
                float xbv = (pooled - mean[f]) * rsqrtf(var[f] + BN_EPS_C) * gamma[f] + beta[f];
                xb[g * HID + f] = xbv;
                xbl[f] = xbv;
            }
        }
    }
    __syncthreads();
    if (tid < 64) {
        float x0 = xbl[tid], x1 = xbl[tid + 64];
        float s0 = x0 * lw[tid * 2 + 0] + x1 * lw[(tid + 64) * 2 + 0];
        float s1h = x0 * lw[tid * 2 + 1] + x1 * lw[(tid + 64) * 2 + 1];
        #pragma unroll
        for (int o = 1; o < 64; o <<= 1) {
            s0 += __shfl_xor(s0, o);
            s1h += __shfl_xor(s1h, o);
        }
        if (tid == 0) {
            out2[g * 2 + 0] = fmaxf(s0 + lb[0], 0.f);
            out2[g * 2 + 1] = fmaxf(s1h + lb[1], 0.f);
        }
    }
}

extern "C" void kernel_launch(void* const* d_in, const int* in_sizes, int n_in,
                              void* d_out, int out_size, void* d_ws, size_t ws_size,
                              hipStream_t stream) {
    const float* x     = (const float*)d_in[0];
    const int*   ei    = (const int*)d_in[1];
    const int*   batch = (const int*)d_in[3];
    const float* W1 = (const float*)d_in[4];
    const float* b1 = (const float*)d_in[5];
    const float* W2 = (const float*)d_in[6];
    const float* b2 = (const float*)d_in[7];
    const float* W3 = (const float*)d_in[8];
    const float* b3 = (const float*)d_in[9];
    const float* gamma = (const float*)d_in[10];
    const float* beta  = (const float*)d_in[11];
    const float* mean  = (const float*)d_in[12];
    const float* var   = (const float*)d_in[13];
    const float* lw = (const float*)d_in[14];
    const float* lb = (const float*)d_in[15];
    float* out = (float*)d_out;

    char* p = (char*)d_ws;
    unsigned short* HWB = (unsigned short*)p;          p += (size_t)NNODES * HID * 2;  // 25.6MB (fp8 uses half)
    unsigned short* AGB = (unsigned short*)p;          p += (size_t)NNODES * HID * 2;  // 25.6MB
    float* DIS    = (float*)p;                         p += (size_t)NNODES * 4;
    float* SELFN  = (float*)p;                         p += (size_t)NNODES * 4;
    int*   ROWPTR = (int*)p;                           p += (size_t)(NNODES + 64) * 4;
    unsigned int* EDGP = (unsigned int*)p;             p += (size_t)NEDGES * 4;
    int*   PAIRS  = (int*)p;                           p += (size_t)NEDGES * 4;   // dedicated (gemm1 overlaps kbC2)
    int*   BTOT   = (int*)p;                           p += 512 * 4;
    int*   BBASE  = (int*)p;                           p += 512 * 4;
    unsigned short* WHL1 = (unsigned short*)p;         p += (size_t)FIN * 128 * 2 * 2;
    unsigned short* WHL2 = (unsigned short*)p;         p += (size_t)HID * 128 * 2 * 2;
    unsigned short* WHL3 = (unsigned short*)p;
    // build-phase aliases (consumed before gather1 writes AGB)
    int*   HIST   = (int*)AGB;                         // NB*NW i (400KB)
    int*   OFF    = HIST + NB * NW;                    // NB*NW i

    const int* srcv = ei;
    const int* dstv = ei + NEDGES;

    // ---- build + layer-1 pipeline with independent-kernel fusion ----
    k_prep<<<512, 256, 0, stream>>>(W1, W2, W3, WHL1, WHL2, WHL3, dstv, HIST);
    kbB2<<<NB, 256, 0, stream>>>(HIST, OFF, BTOT);
    kbT<<<1, 512, 0, stream>>>(BTOT, BBASE, ROWPTR);
    // kbC2 scatter || gemm1 (x @ W1 -> fp8 HWB)
    k_c2g1<<<256 + GEMM_BLKS, 256, 0, stream>>>(srcv, dstv, OFF, BBASE, PAIRS, x, WHL1, HWB);
    kb2y<<<NB, 256, 0, stream>>>(BBASE, PAIRS, ROWPTR, DIS, SELFN);
    kb2z<<<NB, 256, 0, stream>>>(BBASE, PAIRS, ROWPTR, DIS, EDGP);

    const int ggat = NNODES / 16;   // 6250, exact
    dim3 gg(GEMM_BLKS);

    k_gather<1><<<ggat, 256, 0, stream>>>(ROWPTR, EDGP, HWB, SELFN, b1, AGB);
    // layer 2 (A = relu'd bf16 AGB; hwb fp8)
    k_gemm_mfma<HID, 1, 1><<<gg, 256, 0, stream>>>(AGB, WHL2, HWB);
    k_gather<1><<<ggat, 256, 0, stream>>>(ROWPTR, EDGP, HWB, SELFN, b2, AGB);
    // layer 3 (hwb bf16 -- last layer's quantization is undamped, keep precise)
    k_gemm_mfma<HID, 1, 0><<<gg, 256, 0, stream>>>(AGB, WHL3, HWB);
    k_gather<0><<<ggat, 256, 0, stream>>>(ROWPTR, EDGP, HWB, SELFN, b3, AGB);

    // fused pool + BN + head
    k_pool_bn_head<<<NG, 1024, 0, stream>>>(AGB, batch, gamma, beta, mean, var,
                                            lw, lb, out, out + (size_t)NG * HID);
}

// Round 18
// 260.425 us; speedup vs baseline: 1.1067x; 1.0029x over previous
//
#include <hip/hip_runtime.h>

#define NNODES 100000
#define NEDGES 1600000
#define FIN 256
#define HID 128
#define NG 128
#define NB 391            // buckets of 256 nodes (dst>>8)
#define NW 256            // histogram workgroups
#define EPW 6250          // NEDGES / NW
#define GEMM_BLKS 1563    // ceil(NNODES/64)

static constexpr float BN_EPS_C = 1e-5f;

typedef __attribute__((ext_vector_type(8))) short bf16x8;
typedef __attribute__((ext_vector_type(4))) float f32x4;
typedef __attribute__((ext_vector_type(2))) float f32x2;

#if defined(__has_builtin)
#if __has_builtin(__builtin_amdgcn_cvt_pk_f32_fp8)
#define HAS_HWFP8 1
#endif
#endif

__device__ __forceinline__ float b2f(unsigned short u) {
    union { unsigned int i; float f; } c; c.i = ((unsigned int)u) << 16; return c.f;
}
__device__ __forceinline__ unsigned short f2b(float f) {
    union { float f; unsigned int i; } c; c.f = f;
    unsigned int u = c.i;
    u += 0x7fffu + ((u >> 16) & 1u);   // round-to-nearest-even
    return (unsigned short)(u >> 16);
}

// fp8 e4m3fn encode of PRE-SCALED value (caller multiplies by 64).
__device__ __forceinline__ unsigned char f2e8(float f) {
    union { float f; unsigned int u; } c; c.f = f;
    unsigned int s = (c.u >> 24) & 0x80u;
    c.u &= 0x7fffffffu;
    c.f = fminf(fmaxf(c.f, 0.015625f), 448.f);
    unsigned int u = c.u + 0x7ffffu + ((c.u >> 20) & 1u);   // RNE to 3-bit mantissa
    int e = (int)(u >> 23) - 127;
    unsigned int m = (u >> 20) & 7u;
    return (unsigned char)(s | ((unsigned int)(e + 7) << 3) | m);
}

__device__ __forceinline__ float e8byte(unsigned int b) {
    union { unsigned int u; float f; } c;
    c.u = ((b & 0x80u) << 24) | (0x3C000000u + ((b & 0x7fu) << 20));
    return c.f;
}
__device__ __forceinline__ f32x2 e8plo(unsigned int w) {
#ifdef HAS_HWFP8
    return __builtin_amdgcn_cvt_pk_f32_fp8(w, false);
#else
    f32x2 r; r[0] = e8byte(w & 0xffu); r[1] = e8byte((w >> 8) & 0xffu); return r;
#endif
}
__device__ __forceinline__ f32x2 e8phi(unsigned int w) {
#ifdef HAS_HWFP8
    return __builtin_amdgcn_cvt_pk_f32_fp8(w, true);
#else
    f32x2 r; r[0] = e8byte((w >> 16) & 0xffu); r[1] = e8byte(w >> 24); return r;
#endif
}
__device__ __forceinline__ f32x2 bdec(unsigned int u) {
    union { unsigned int i[2]; f32x2 f; } c;
    c.i[0] = u << 16;
    c.i[1] = u & 0xffff0000u;
    return c.f;
}

// LDS 16B-granule swizzle: spreads the stride-256B A-staging writes across banks.
// Applied identically at write (staging) and read (fragment load) of Ah0/Ah1.
__device__ __forceinline__ int aswz(int g) { return g ^ ((g >> 4) & 3); }

// ---- shared GEMM body (MFMA split-bf16). MODE 0: A fp32 hi/lo (3 MFMAs);
// MODE 1: A bf16 (2 MFMAs). OUT8: hwb = fp8 x64, else bf16. ----
template<int K, int MODE, int OUT8>
__device__ __forceinline__ void gemm_body(int blk,
                                          const void* __restrict__ Araw,
                                          const unsigned short* __restrict__ whl,
                                          void* __restrict__ hwbv) {
    __shared__ __align__(16) unsigned short Ah0[2048];
    __shared__ __align__(16) unsigned short Ah1[2048];
    __shared__ __align__(16) unsigned short Bs[8192];

    const int tid = threadIdx.x;
    const int w = tid >> 6;
    const int lane = tid & 63;
    const int m0 = blk * 64;
    const int ar = tid >> 2;
    const int ak = (tid & 3) * 8;
    const int adst = aswz(((ar >> 4) * 64) + (ar & 15) + 16 * (ak >> 3)) * 8;
    const int ards = aswz(w * 64 + lane) * 8;

    f32x4 acc[8] = {};

    for (int kt = 0; kt < K; kt += 32) {
        if (MODE == 0) {
            const float* A = (const float*)Araw;
            float4 v0 = {0.f,0.f,0.f,0.f}, v1 = {0.f,0.f,0.f,0.f};
            int grow = m0 + ar;
            if (grow < NNODES) {
                const float* s = A + (size_t)grow * K + kt + ak;
                v0 = *(const float4*)(s);
                v1 = *(const float4*)(s + 4);
            }
            float av[8];
            *(float4*)(av) = v0; *(float4*)(av + 4) = v1;
            bf16x8 hv, lv;
            #pragma unroll
            for (int j = 0; j < 8; ++j) {
                unsigned short h = f2b(av[j]);
                hv[j] = (short)h;
                lv[j] = (short)f2b(av[j] - b2f(h));
            }
            *(bf16x8*)&Ah0[adst] = hv;
            *(bf16x8*)&Ah1[adst] = lv;
        } else {
            const unsigned short* A = (const unsigned short*)Araw;
            bf16x8 hv = {};
            int grow = m0 + ar;
            if (grow < NNODES)
                hv = *(const bf16x8*)(A + (size_t)grow * K + kt + ak);
            *(bf16x8*)&Ah0[adst] = hv;
        }
        {
            const float4* bsrc = (const float4*)(whl + (size_t)(kt >> 5) * 8192);
            float4* bdst = (float4*)Bs;
            #pragma unroll
            for (int i = 0; i < 4; ++i) bdst[tid * 4 + i] = bsrc[tid * 4 + i];
        }
        __syncthreads();
        bf16x8 a0 = *(const bf16x8*)&Ah0[ards];
        bf16x8 a1;
        if (MODE == 0) a1 = *(const bf16x8*)&Ah1[ards];
        #pragma unroll
        for (int t = 0; t < 8; ++t) {
            bf16x8 b0 = *(const bf16x8*)&Bs[(t * 64 + lane) * 8];
            bf16x8 b1 = *(const bf16x8*)&Bs[4096 + (t * 64 + lane) * 8];
            acc[t] = __builtin_amdgcn_mfma_f32_16x16x32_bf16(a0, b0, acc[t], 0, 0, 0);
            acc[t] = __builtin_amdgcn_mfma_f32_16x16x32_bf16(a0, b1, acc[t], 0, 0, 0);
            if (MODE == 0)
                acc[t] = __builtin_amdgcn_mfma_f32_16x16x32_bf16(a1, b0, acc[t], 0, 0, 0);
        }
        __syncthreads();
    }

    const int colLo = lane & 15;
    const int gq = lane >> 4;
    #pragma unroll
    for (int i = 0; i < 4; ++i) {
        int row = m0 + w * 16 + gq * 4 + i;
        if (row < NNODES) {
            #pragma unroll
            for (int t = 0; t < 8; ++t) {
                int col = t * 16 + colLo;
                float v = acc[t][i];
                if (OUT8) {
                    ((unsigned char*)hwbv)[(size_t)row * HID + col] = f2e8(v * 64.f);
                } else {
                    ((unsigned short*)hwbv)[(size_t)row * HID + col] = f2b(v);
                }
            }
        }
    }
}

// FUSED: wconv3 (blocks 0..255) || kbA histogram (blocks 256..511)
__global__ __launch_bounds__(256) void k_prep(const float* __restrict__ W1,
                                              const float* __restrict__ W2,
                                              const float* __restrict__ W3,
                                              unsigned short* __restrict__ whl1,
                                              unsigned short* __restrict__ whl2,
                                              unsigned short* __restrict__ whl3,
                                              const int* __restrict__ dst,
                                              int* __restrict__ hist) {
    if (blockIdx.x < 256) {
        int idx = blockIdx.x * 256 + threadIdx.x;
        const float* W; unsigned short* whl;
        if (idx < FIN * 128) { W = W1; whl = whl1; }
        else if (idx < (FIN + HID) * 128) { W = W2; whl = whl2; idx -= FIN * 128; }
        else { W = W3; whl = whl3; idx -= (FIN + HID) * 128; }
        int k = idx >> 7, c = idx & 127;
        float v = W[k * 128 + c];
        unsigned short hi = f2b(v);
        unsigned short lo = f2b(v - b2f(hi));
        int kstep = k >> 5, kk = k & 31, g = kk >> 3, j = kk & 7;
        int tile = c >> 4, lane = (c & 15) + 16 * g;
        size_t b0 = ((((size_t)kstep * 2 + 0) * 8 + tile) * 64 + lane) * 8 + j;
        size_t b1 = ((((size_t)kstep * 2 + 1) * 8 + tile) * 64 + lane) * 8 + j;
        whl[b0] = hi;
        whl[b1] = lo;
    } else {
        __shared__ int h[NB];
        int w = blockIdx.x - 256, t = threadIdx.x;
        for (int i = t; i < NB; i += 256) h[i] = 0;
        __syncthreads();
        int base = w * EPW;
        for (int i = t; i < EPW; i += 256) atomicAdd(&h[dst[base + i] >> 8], 1);
        __syncthreads();
        for (int i = t; i < NB; i += 256) hist[i * NW + w] = h[i];
    }
}

// pass B: per-bucket exclusive scan across WGs (relative) + bucket totals
__global__ __launch_bounds__(256) void kbB2(const int* __restrict__ hist,
                                            int* __restrict__ off,
                                            int* __restrict__ btot) {
    __shared__ int s[NW];
    int b = blockIdx.x, t = threadIdx.x;
    int v = hist[b * NW + t];
    s[t] = v;
    __syncthreads();
    for (int o = 1; o < NW; o <<= 1) {
        int a = (t >= o) ? s[t - o] : 0;
        __syncthreads();
        s[t] += a;
        __syncthreads();
    }
    off[b * NW + t] = s[t] - v;
    if (t == NW - 1) btot[b] = s[t];
}

// bucket-base exclusive scan (one block)
__global__ __launch_bounds__(512) void kbT(const int* __restrict__ btot,
                                           int* __restrict__ bbase,
                                           int* __restrict__ rowptr) {
    __shared__ int s[512];
    int t = threadIdx.x;
    int v = (t < NB) ? btot[t] : 0;
    s[t] = v;
    __syncthreads();
    for (int o = 1; o < 512; o <<= 1) {
        int a = (t >= o) ? s[t - o] : 0;
        __syncthreads();
        s[t] += a;
        __syncthreads();
    }
    if (t < NB) bbase[t] = s[t] - v;
    if (t == NB - 1) { bbase[NB] = s[t]; rowptr[NNODES] = NEDGES; }
}

// FUSED: kbC2 scatter (blocks 0..255) || gemm1 <FIN,0,1> (blocks 256..1818)
__global__ __launch_bounds__(256) void k_c2g1(const int* __restrict__ src,
                                              const int* __restrict__ dst,
                                              const int* __restrict__ off,
                                              const int* __restrict__ bbase,
                                              int* __restrict__ pairs,
                                              const float* __restrict__ x,
                                              const unsigned short* __restrict__ whl1,
                                              void* __restrict__ hwbv) {
    if (blockIdx.x < 256) {
        __shared__ int cur[NB];
        int w = blockIdx.x, t = threadIdx.x;
        for (int i = t; i < NB; i += 256) cur[i] = off[i * NW + w] + bbase[i];
        __syncthreads();
        int base = w * EPW;
        for (int i = t; i < EPW; i += 256) {
            int d = dst[base + i];
            int pos = atomicAdd(&cur[d >> 8], 1);
            pairs[pos] = (src[base + i] << 8) | (d & 255);
        }
    } else {
        gemm_body<FIN, 0, 1>(blockIdx.x - 256, x, whl1, hwbv);
    }
}

// per bucket: count per node (LDS), local scan -> rowptr/dis/selfn
__global__ __launch_bounds__(256) void kb2y(const int* __restrict__ bbase,
                                            const int* __restrict__ pairs,
                                            int* __restrict__ rowptr,
                                            float* __restrict__ dis,
                                            float* __restrict__ selfn) {
    int b = blockIdx.x;
    int nbase = b * 256;
    int nmax = NNODES - nbase; if (nmax > 256) nmax = 256;
    __shared__ int cnt[256];
    __shared__ int cur[256];
    int t = threadIdx.x;
    cnt[t] = 0;
    __syncthreads();
    int beg = bbase[b], end = bbase[b + 1];
    for (int i = beg + t; i < end; i += 256) atomicAdd(&cnt[pairs[i] & 255], 1);
    __syncthreads();
    int v = cnt[t];
    cur[t] = v;
    __syncthreads();
    for (int o = 1; o < 256; o <<= 1) {
        int a = (t >= o) ? cur[t - o] : 0;
        __syncthreads();
        cur[t] += a;
        __syncthreads();
    }
    if (t < nmax) {
        rowptr[nbase + t] = cur[t] - v + beg;
        float d = 1.0f + (float)v;
        dis[nbase + t] = rsqrtf(d);
        selfn[nbase + t] = 1.0f / d;
    }
}

// per bucket: place pairs directly as packed edges (src<<15 | u15 weight)
__global__ __launch_bounds__(256) void kb2z(const int* __restrict__ bbase,
                                            const int* __restrict__ pairs,
                                            const int* __restrict__ rowptr,
                                            const float* __restrict__ dis,
                                            unsigned int* __restrict__ edgp) {
    int b = blockIdx.x;
    int nbase = b * 256;
    int nmax = NNODES - nbase; if (nmax > 256) nmax = 256;
    __shared__ int cur[256];
    __shared__ float disl[256];
    int t = threadIdx.x;
    if (t < nmax) {
        cur[t] = rowptr[nbase + t];
        disl[t] = dis[nbase + t];
    }
    __syncthreads();
    int beg = bbase[b], end = bbase[b + 1];
    for (int i = beg + t; i < end; i += 256) {
        int p = pairs[i];
        int s = p >> 8;
        float w = dis[s] * disl[p & 255];
        unsigned int u = (unsigned int)(w * 32767.f + 0.5f);
        int pos = atomicAdd(&cur[p & 255], 1);
        edgp[pos] = ((unsigned int)s << 15) | u;
    }
}

// standalone GEMM for layers 2/3
template<int K, int MODE, int OUT8>
__global__ __launch_bounds__(256) void k_gemm_mfma(const void* __restrict__ Araw,
                                                   const unsigned short* __restrict__ whl,
                                                   void* __restrict__ hwbv) {
    gemm_body<K, MODE, OUT8>(blockIdx.x, Araw, whl, hwbv);
}

// SUBWAVE-PER-NODE gather: 16-lane subwave owns one node. fp8: 8 edges/iter;
// bf16: 4 edges/iter. Self-term inline from hwb[node]*selfn + bias.
template<int IN8>
__global__ __launch_bounds__(256) void k_gather(const int* __restrict__ rowptr,
                                                const unsigned int* __restrict__ edgp,
                                                const void* __restrict__ hwbv,
                                                const float* __restrict__ selfn,
                                                const float* __restrict__ bias,
                                                unsigned short* __restrict__ agb) {
    const int lane = threadIdx.x & 63;
    const int sub = lane >> 4;
    const int l4 = lane & 15;
    const int node = blockIdx.x * 16 + ((threadIdx.x >> 6) << 2) + sub;
    int beg = rowptr[node], end = rowptr[node + 1];
    const float q = IN8 ? (1.0f / (32767.0f * 64.0f)) : (1.0f / 32767.0f);
    const unsigned char* hb = (const unsigned char*)hwbv;
    f32x2 a0 = {0.f,0.f}, a1 = {0.f,0.f}, a2 = {0.f,0.f}, a3 = {0.f,0.f};
    int e = beg;
    if (IN8) {
        for (; e + 7 < end; e += 8) {
            unsigned int p0 = edgp[e], p1 = edgp[e + 1];
            unsigned int p2 = edgp[e + 2], p3 = edgp[e + 3];
            unsigned int p4 = edgp[e + 4], p5 = edgp[e + 5];
            unsigned int p6 = edgp[e + 6], p7 = edgp[e + 7];
            uint2 v0 = *(const uint2*)(hb + (size_t)(p0 >> 15) * HID + l4 * 8);
            uint2 v1 = *(const uint2*)(hb + (size_t)(p1 >> 15) * HID + l4 * 8);
            uint2 v2 = *(const uint2*)(hb + (size_t)(p2 >> 15) * HID + l4 * 8);
            uint2 v3 = *(const uint2*)(hb + (size_t)(p3 >> 15) * HID + l4 * 8);
            uint2 v4 = *(const uint2*)(hb + (size_t)(p4 >> 15) * HID + l4 * 8);
            uint2 v5 = *(const uint2*)(hb + (size_t)(p5 >> 15) * HID + l4 * 8);
            uint2 v6 = *(const uint2*)(hb + (size_t)(p6 >> 15) * HID + l4 * 8);
            uint2 v7 = *(const uint2*)(hb + (size_t)(p7 >> 15) * HID + l4 * 8);
            float w0 = (float)(p0 & 0x7fffu) * q, w1 = (float)(p1 & 0x7fffu) * q;
            float w2 = (float)(p2 & 0x7fffu) * q, w3 = (float)(p3 & 0x7fffu) * q;
            float w4 = (float)(p4 & 0x7fffu) * q, w5 = (float)(p5 & 0x7fffu) * q;
            float w6 = (float)(p6 & 0x7fffu) * q, w7 = (float)(p7 & 0x7fffu) * q;
            f32x2 wa = {w0, w0}, wb = {w1, w1}, wc = {w2, w2}, wd = {w3, w3};
            f32x2 we = {w4, w4}, wf = {w5, w5}, wg = {w6, w6}, wh = {w7, w7};
            a0 += e8plo(v0.x) * wa; a1 += e8phi(v0.x) * wa;
            a2 += e8plo(v0.y) * wa; a3 += e8phi(v0.y) * wa;
            a0 += e8plo(v1.x) * wb; a1 += e8phi(v1.x) * wb;
            a2 += e8plo(v1.y) * wb; a3 += e8phi(v1.y) * wb;
            a0 += e8plo(v2.x) * wc; a1 += e8phi(v2.x) * wc;
            a2 += e8plo(v2.y) * wc; a3 += e8phi(v2.y) * wc;
            a0 += e8plo(v3.x) * wd; a1 += e8phi(v3.x) * wd;
            a2 += e8plo(v3.y) * wd; a3 += e8phi(v3.y) * wd;
            a0 += e8plo(v4.x) * we; a1 += e8phi(v4.x) * we;
            a2 += e8plo(v4.y) * we; a3 += e8phi(v4.y) * we;
            a0 += e8plo(v5.x) * wf; a1 += e8phi(v5.x) * wf;
            a2 += e8plo(v5.y) * wf; a3 += e8phi(v5.y) * wf;
            a0 += e8plo(v6.x) * wg; a1 += e8phi(v6.x) * wg;
            a2 += e8plo(v6.y) * wg; a3 += e8phi(v6.y) * wg;
            a0 += e8plo(v7.x) * wh; a1 += e8phi(v7.x) * wh;
            a2 += e8plo(v7.y) * wh; a3 += e8phi(v7.y) * wh;
        }
    } else {
        for (; e + 3 < end; e += 4) {
            unsigned int p0 = edgp[e], p1 = edgp[e + 1];
            unsigned int p2 = edgp[e + 2], p3 = edgp[e + 3];
            float w0 = (float)(p0 & 0x7fffu) * q;
            float w1 = (float)(p1 & 0x7fffu) * q;
            float w2 = (float)(p2 & 0x7fffu) * q;
            float w3 = (float)(p3 & 0x7fffu) * q;
            f32x2 wa = {w0, w0}, wb = {w1, w1}, wc = {w2, w2}, wd = {w3, w3};
            size_t r0 = (size_t)(p0 >> 15), r1 = (size_t)(p1 >> 15);
            size_t r2 = (size_t)(p2 >> 15), r3 = (size_t)(p3 >> 15);
            uint4 v0 = *(const uint4*)(hb + r0 * (HID * 2) + l4 * 16);
            uint4 v1 = *(const uint4*)(hb + r1 * (HID * 2) + l4 * 16);
            uint4 v2 = *(const uint4*)(hb + r2 * (HID * 2) + l4 * 16);
            uint4 v3 = *(const uint4*)(hb + r3 * (HID * 2) + l4 * 16);
            a0 += bdec(v0.x) * wa; a1 += bdec(v0.y) * wa;
            a2 += bdec(v0.z) * wa; a3 += bdec(v0.w) * wa;
            a0 += bdec(v1.x) * wb; a1 += bdec(v1.y) * wb;
            a2 += bdec(v1.z) * wb; a3 += bdec(v1.w) * wb;
            a0 += bdec(v2.x) * wc; a1 += bdec(v2.y) * wc;
            a2 += bdec(v2.z) * wc; a3 += bdec(v2.w) * wc;
            a0 += bdec(v3.x) * wd; a1 += bdec(v3.y) * wd;
            a2 += bdec(v3.z) * wd; a3 += bdec(v3.w) * wd;
        }
    }
    for (; e < end; ++e) {
        unsigned int p = edgp[e];
        float w = (float)(p & 0x7fffu) * q;
        f32x2 wa = {w, w};
        size_t r = (size_t)(p >> 15);
        if (IN8) {
            uint2 v = *(const uint2*)(hb + r * HID + l4 * 8);
            a0 += e8plo(v.x) * wa; a1 += e8phi(v.x) * wa;
            a2 += e8plo(v.y) * wa; a3 += e8phi(v.y) * wa;
        } else {
            uint4 v = *(const uint4*)(hb + r * (HID * 2) + l4 * 16);
            a0 += bdec(v.x) * wa; a1 += bdec(v.y) * wa;
            a2 += bdec(v.z) * wa; a3 += bdec(v.w) * wa;
        }
    }
    // self-term: hw[node] * selfn + bias, relu, store bf16
    float sn = selfn[node] * (IN8 ? (1.0f / 64.0f) : 1.0f);
    f32x2 sn2 = {sn, sn};
    f32x2 h0, h1, h2, h3;
    if (IN8) {
        uint2 v = *(const uint2*)(hb + (size_t)node * HID + l4 * 8);
        h0 = e8plo(v.x); h1 = e8phi(v.x); h2 = e8plo(v.y); h3 = e8phi(v.y);
    } else {
        uint4 v = *(const uint4*)(hb + (size_t)node * (HID * 2) + l4 * 16);
        h0 = bdec(v.x); h1 = bdec(v.y); h2 = bdec(v.z); h3 = bdec(v.w);
    }
    float4 bA = *(const float4*)&bias[l4 * 8];
    float4 bB = *(const float4*)&bias[l4 * 8 + 4];
    a0 += h0 * sn2; a1 += h1 * sn2; a2 += h2 * sn2; a3 += h3 * sn2;
    float r0 = fmaxf(a0[0] + bA.x, 0.f), r1 = fmaxf(a0[1] + bA.y, 0.f);
    float r2 = fmaxf(a1[0] + bA.z, 0.f), r3 = fmaxf(a1[1] + bA.w, 0.f);
    float r4 = fmaxf(a2[0] + bB.x, 0.f), r5 = fmaxf(a2[1] + bB.y, 0.f);
    float r6 = fmaxf(a3[0] + bB.z, 0.f), r7 = fmaxf(a3[1] + bB.w, 0.f);
    uint4 o;
    o.x = (unsigned int)f2b(r0) | ((unsigned int)f2b(r1) << 16);
    o.y = (unsigned int)f2b(r2) | ((unsigned int)f2b(r3) << 16);
    o.z = (unsigned int)f2b(r4) | ((unsigned int)f2b(r5) << 16);
    o.w = (unsigned int)f2b(r6) | ((unsigned int)f2b(r7) << 16);
    *(uint4*)(agb + (size_t)node * HID + l4 * 8) = o;
}

// fused pool + BN + head. One graph per block, 1024 threads.
__global__ __launch_bounds__(1024) void k_pool_bn_head(const unsigned short* __restrict__ h,
                                                       const int* __restrict__ batch,
                                                       const float* __restrict__ gamma,
                                                       const float* __restrict__ beta,
                                                       const float* __restrict__ mean,
                                                       const float* __restrict__ var,
                                                       const float* __restrict__ lw,
                                                       const float* __restrict__ lb,
                                                       float* __restrict__ xb,
                                                       float* __restrict__ out2) {
    int g = blockIdx.x;
    int tid = threadIdx.x;
    int fg = tid & 15;
    int r = tid >> 4;
    __shared__ int bounds[2];
    if (tid < 2) {
        int target = g + tid;
        int a = 0, b = NNODES;
        while (a < b) { int m = (a + b) >> 1; if (batch[m] < target) a = m + 1; else b = m; }
        bounds[tid] = a;
    }
    __syncthreads();
    int s1 = bounds[0], e1 = bounds[1];
    f32x2 acc[4] = {};
    for (int i = s1 + r; i < e1; i += 64) {
        uint4 v = *(const uint4*)(h + (size_t)i * HID + fg * 8);
        acc[0] += bdec(v.x); acc[1] += bdec(v.y); acc[2] += bdec(v.z); acc[3] += bdec(v.w);
    }
    __shared__ f32x2 red[64][16][4];   // 32KB
    #pragma unroll
    for (int j = 0; j < 4; ++j) red[r][fg][j] = acc[j];
    __syncthreads();
    for (int off = 32; off >= 1; off >>= 1) {
        if (r < off) {
            #pragma unroll
            for (int j = 0; j < 4; ++j) red[r][fg][j] += red[r + off][fg][j];
        }
        __syncthreads();
    }
    __shared__ float xbl[128];
    if (r == 0) {
        float cnt = (float)((e1 - s1) > 0 ? (e1 - s1) : 1);
        float inv = 1.0f / cnt;
        #pragma unroll
        for (int j = 0; j < 4; ++j) {
            #pragma unroll
            for (int k2 = 0; k2 < 2; ++k2) {
                int f = fg * 8 + j * 2 + k2;
                float pooled = red[0][fg][j][k2] * inv;
                float xbv = (pooled - mean[f]) * rsqrtf(var[f] + BN_EPS_C) * gamma[f] + beta[f];
                xb[g * HID + f] = xbv;
                xbl[f] = xbv;
            }
        }
    }
    __syncthreads();
    if (tid < 64) {
        float x0 = xbl[tid], x1 = xbl[tid + 64];
        float s0 = x0 * lw[tid * 2 + 0] + x1 * lw[(tid + 64) * 2 + 0];
        float s1h = x0 * lw[tid * 2 + 1] + x1 * lw[(tid + 64) * 2 + 1];
        #pragma unroll
        for (int o = 1; o < 64; o <<= 1) {
            s0 += __shfl_xor(s0, o);
            s1h += __shfl_xor(s1h, o);
        }
        if (tid == 0) {
            out2[g * 2 + 0] = fmaxf(s0 + lb[0], 0.f);
            out2[g * 2 + 1] = fmaxf(s1h + lb[1], 0.f);
        }
    }
}

extern "C" void kernel_launch(void* const* d_in, const int* in_sizes, int n_in,
                              void* d_out, int out_size, void* d_ws, size_t ws_size,
                              hipStream_t stream) {
    const float* x     = (const float*)d_in[0];
    const int*   ei    = (const int*)d_in[1];
    const int*   batch = (const int*)d_in[3];
    const float* W1 = (const float*)d_in[4];
    const float* b1 = (const float*)d_in[5];
    const float* W2 = (const float*)d_in[6];
    const float* b2 = (const float*)d_in[7];
    const float* W3 = (const float*)d_in[8];
    const float* b3 = (const float*)d_in[9];
    const float* gamma = (const float*)d_in[10];
    const float* beta  = (const float*)d_in[11];
    const float* mean  = (const float*)d_in[12];
    const float* var   = (const float*)d_in[13];
    const float* lw = (const float*)d_in[14];
    const float* lb = (const float*)d_in[15];
    float* out = (float*)d_out;

    char* p = (char*)d_ws;
    unsigned short* HWB = (unsigned short*)p;          p += (size_t)NNODES * HID * 2;  // 25.6MB (fp8 uses half)
    unsigned short* AGB = (unsigned short*)p;          p += (size_t)NNODES * HID * 2;  // 25.6MB
    float* DIS    = (float*)p;                         p += (size_t)NNODES * 4;
    float* SELFN  = (float*)p;                         p += (size_t)NNODES * 4;
    int*   ROWPTR = (int*)p;                           p += (size_t)(NNODES + 64) * 4;
    unsigned int* EDGP = (unsigned int*)p;             p += (size_t)NEDGES * 4;
    int*   PAIRS  = (int*)p;                           p += (size_t)NEDGES * 4;   // dedicated (gemm1 overlaps kbC2)
    int*   BTOT   = (int*)p;                           p += 512 * 4;
    int*   BBASE  = (int*)p;                           p += 512 * 4;
    unsigned short* WHL1 = (unsigned short*)p;         p += (size_t)FIN * 128 * 2 * 2;
    unsigned short* WHL2 = (unsigned short*)p;         p += (size_t)HID * 128 * 2 * 2;
    unsigned short* WHL3 = (unsigned short*)p;
    // build-phase aliases (consumed before gather1 writes AGB)
    int*   HIST   = (int*)AGB;                         // NB*NW i (400KB)
    int*   OFF    = HIST + NB * NW;                    // NB*NW i

    const int* srcv = ei;
    const int* dstv = ei + NEDGES;

    // ---- build + layer-1 pipeline with independent-kernel fusion ----
    k_prep<<<512, 256, 0, stream>>>(W1, W2, W3, WHL1, WHL2, WHL3, dstv, HIST);
    kbB2<<<NB, 256, 0, stream>>>(HIST, OFF, BTOT);
    kbT<<<1, 512, 0, stream>>>(BTOT, BBASE, ROWPTR);
    // kbC2 scatter || gemm1 (x @ W1 -> fp8 HWB)
    k_c2g1<<<256 + GEMM_BLKS, 256, 0, stream>>>(srcv, dstv, OFF, BBASE, PAIRS, x, WHL1, HWB);
    kb2y<<<NB, 256, 0, stream>>>(BBASE, PAIRS, ROWPTR, DIS, SELFN);
    kb2z<<<NB, 256, 0, stream>>>(BBASE, PAIRS, ROWPTR, DIS, EDGP);

    const int ggat = NNODES / 16;   // 6250, exact
    dim3 gg(GEMM_BLKS);

    k_gather<1><<<ggat, 256, 0, stream>>>(ROWPTR, EDGP, HWB, SELFN, b1, AGB);
    // layer 2 (A = relu'd bf16 AGB; hwb fp8)
    k_gemm_mfma<HID, 1, 1><<<gg, 256, 0, stream>>>(AGB, WHL2, HWB);
    k_gather<1><<<ggat, 256, 0, stream>>>(ROWPTR, EDGP, HWB, SELFN, b2, AGB);
    // layer 3 (hwb bf16 -- last layer's quantization is undamped, keep precise)
    k_gemm_mfma<HID, 1, 0><<<gg, 256, 0, stream>>>(AGB, WHL3, HWB);
    k_gather<0><<<ggat, 256, 0, stream>>>(ROWPTR, EDGP, HWB, SELFN, b3, AGB);

    // fused pool + BN + head
    k_pool_bn_head<<<NG, 1024, 0, stream>>>(AGB, batch, gamma, beta, mean, var,
                                            lw, lb, out, out + (size_t)NG * HID);
}

// Round 19
// 255.251 us; speedup vs baseline: 1.1291x; 1.0203x over previous
//
#include <hip/hip_runtime.h>

#define NNODES 100000
#define NEDGES 1600000
#define FIN 256
#define HID 128
#define NG 128
#define NB 391            // buckets of 256 nodes (dst>>8)
#define NW 256            // histogram workgroups
#define EPW 6250          // NEDGES / NW
#define GEMM_BLKS 1563    // ceil(NNODES/64)

static constexpr float BN_EPS_C = 1e-5f;

typedef __attribute__((ext_vector_type(8))) short bf16x8;
typedef __attribute__((ext_vector_type(4))) float f32x4;
typedef __attribute__((ext_vector_type(2))) float f32x2;

#if defined(__has_builtin)
#if __has_builtin(__builtin_amdgcn_cvt_pk_f32_fp8)
#define HAS_HWFP8 1
#endif
#endif

__device__ __forceinline__ float b2f(unsigned short u) {
    union { unsigned int i; float f; } c; c.i = ((unsigned int)u) << 16; return c.f;
}
__device__ __forceinline__ unsigned short f2b(float f) {
    union { float f; unsigned int i; } c; c.f = f;
    unsigned int u = c.i;
    u += 0x7fffu + ((u >> 16) & 1u);   // round-to-nearest-even
    return (unsigned short)(u >> 16);
}

// fp8 e4m3fn encode of PRE-SCALED value (caller multiplies by 64).
__device__ __forceinline__ unsigned char f2e8(float f) {
    union { float f; unsigned int u; } c; c.f = f;
    unsigned int s = (c.u >> 24) & 0x80u;
    c.u &= 0x7fffffffu;
    c.f = fminf(fmaxf(c.f, 0.015625f), 448.f);
    unsigned int u = c.u + 0x7ffffu + ((c.u >> 20) & 1u);   // RNE to 3-bit mantissa
    int e = (int)(u >> 23) - 127;
    unsigned int m = (u >> 20) & 7u;
    return (unsigned char)(s | ((unsigned int)(e + 7) << 3) | m);
}

__device__ __forceinline__ float e8byte(unsigned int b) {
    union { unsigned int u; float f; } c;
    c.u = ((b & 0x80u) << 24) | (0x3C000000u + ((b & 0x7fu) << 20));
    return c.f;
}
__device__ __forceinline__ f32x2 e8plo(unsigned int w) {
#ifdef HAS_HWFP8
    return __builtin_amdgcn_cvt_pk_f32_fp8(w, false);
#else
    f32x2 r; r[0] = e8byte(w & 0xffu); r[1] = e8byte((w >> 8) & 0xffu); return r;
#endif
}
__device__ __forceinline__ f32x2 e8phi(unsigned int w) {
#ifdef HAS_HWFP8
    return __builtin_amdgcn_cvt_pk_f32_fp8(w, true);
#else
    f32x2 r; r[0] = e8byte((w >> 16) & 0xffu); r[1] = e8byte(w >> 24); return r;
#endif
}
__device__ __forceinline__ f32x2 bdec(unsigned int u) {
    union { unsigned int i[2]; f32x2 f; } c;
    c.i[0] = u << 16;
    c.i[1] = u & 0xffff0000u;
    return c.f;
}

// LDS 16B-granule swizzle (A-staging write/read spread across banks)
__device__ __forceinline__ int aswz(int g) { return g ^ ((g >> 4) & 3); }

// ---- shared GEMM body (MFMA bf16). MODE 0: A fp32 hi/lo (3 MFMAs);
// MODE 1: A bf16 (2 MFMAs, W hi/lo); MODE 2: A fp32 -> bf16 hi only (1 MFMA).
// OUT8: hwb = fp8 x64, else bf16. ----
template<int K, int MODE, int OUT8>
__device__ __forceinline__ void gemm_body(int blk,
                                          const void* __restrict__ Araw,
                                          const unsigned short* __restrict__ whl,
                                          void* __restrict__ hwbv) {
    __shared__ __align__(16) unsigned short Ah0[2048];
    __shared__ __align__(16) unsigned short Ah1[(MODE == 0) ? 2048 : 16];
    __shared__ __align__(16) unsigned short Bs[(MODE == 2) ? 4096 : 8192];

    const int tid = threadIdx.x;
    const int w = tid >> 6;
    const int lane = tid & 63;
    const int m0 = blk * 64;
    const int ar = tid >> 2;
    const int ak = (tid & 3) * 8;
    const int adst = aswz(((ar >> 4) * 64) + (ar & 15) + 16 * (ak >> 3)) * 8;
    const int ards = aswz(w * 64 + lane) * 8;

    f32x4 acc[8] = {};

    for (int kt = 0; kt < K; kt += 32) {
        if (MODE == 0 || MODE == 2) {
            const float* A = (const float*)Araw;
            float4 v0 = {0.f,0.f,0.f,0.f}, v1 = {0.f,0.f,0.f,0.f};
            int grow = m0 + ar;
            if (grow < NNODES) {
                const float* s = A + (size_t)grow * K + kt + ak;
                v0 = *(const float4*)(s);
                v1 = *(const float4*)(s + 4);
            }
            float av[8];
            *(float4*)(av) = v0; *(float4*)(av + 4) = v1;
            bf16x8 hv;
            #pragma unroll
            for (int j = 0; j < 8; ++j) hv[j] = (short)f2b(av[j]);
            *(bf16x8*)&Ah0[adst] = hv;
            if (MODE == 0) {
                bf16x8 lv;
                #pragma unroll
                for (int j = 0; j < 8; ++j)
                    lv[j] = (short)f2b(av[j] - b2f((unsigned short)hv[j]));
                *(bf16x8*)&Ah1[adst] = lv;
            }
        } else {
            const unsigned short* A = (const unsigned short*)Araw;
            bf16x8 hv = {};
            int grow = m0 + ar;
            if (grow < NNODES)
                hv = *(const bf16x8*)(A + (size_t)grow * K + kt + ak);
            *(bf16x8*)&Ah0[adst] = hv;
        }
        {
            const float4* bsrc = (const float4*)(whl + (size_t)(kt >> 5) * 8192);
            float4* bdst = (float4*)Bs;
            if (MODE == 2) {
                #pragma unroll
                for (int i = 0; i < 2; ++i) bdst[tid * 2 + i] = bsrc[tid * 2 + i];
            } else {
                #pragma unroll
                for (int i = 0; i < 4; ++i) bdst[tid * 4 + i] = bsrc[tid * 4 + i];
            }
        }
        __syncthreads();
        bf16x8 a0 = *(const bf16x8*)&Ah0[ards];
        bf16x8 a1;
        if (MODE == 0) a1 = *(const bf16x8*)&Ah1[ards];
        #pragma unroll
        for (int t = 0; t < 8; ++t) {
            bf16x8 b0 = *(const bf16x8*)&Bs[(t * 64 + lane) * 8];
            acc[t] = __builtin_amdgcn_mfma_f32_16x16x32_bf16(a0, b0, acc[t], 0, 0, 0);
            if (MODE != 2) {
                bf16x8 b1 = *(const bf16x8*)&Bs[4096 + (t * 64 + lane) * 8];
                acc[t] = __builtin_amdgcn_mfma_f32_16x16x32_bf16(a0, b1, acc[t], 0, 0, 0);
                if (MODE == 0)
                    acc[t] = __builtin_amdgcn_mfma_f32_16x16x32_bf16(a1, b0, acc[t], 0, 0, 0);
            }
        }
        __syncthreads();
    }

    const int colLo = lane & 15;
    const int gq = lane >> 4;
    #pragma unroll
    for (int i = 0; i < 4; ++i) {
        int row = m0 + w * 16 + gq * 4 + i;
        if (row < NNODES) {
            #pragma unroll
            for (int t = 0; t < 8; ++t) {
                int col = t * 16 + colLo;
                float v = acc[t][i];
                if (OUT8) {
                    ((unsigned char*)hwbv)[(size_t)row * HID + col] = f2e8(v * 64.f);
                } else {
                    ((unsigned short*)hwbv)[(size_t)row * HID + col] = f2b(v);
                }
            }
        }
    }
}

// FUSED: wconv3 (blocks 0..255) || kbA histogram (blocks 256..511)
__global__ __launch_bounds__(256) void k_prep(const float* __restrict__ W1,
                                              const float* __restrict__ W2,
                                              const float* __restrict__ W3,
                                              unsigned short* __restrict__ whl1,
                                              unsigned short* __restrict__ whl2,
                                              unsigned short* __restrict__ whl3,
                                              const int* __restrict__ dst,
                                              int* __restrict__ hist) {
    if (blockIdx.x < 256) {
        int idx = blockIdx.x * 256 + threadIdx.x;
        const float* W; unsigned short* whl;
        if (idx < FIN * 128) { W = W1; whl = whl1; }
        else if (idx < (FIN + HID) * 128) { W = W2; whl = whl2; idx -= FIN * 128; }
        else { W = W3; whl = whl3; idx -= (FIN + HID) * 128; }
        int k = idx >> 7, c = idx & 127;
        float v = W[k * 128 + c];
        unsigned short hi = f2b(v);
        unsigned short lo = f2b(v - b2f(hi));
        int kstep = k >> 5, kk = k & 31, g = kk >> 3, j = kk & 7;
        int tile = c >> 4, lane = (c & 15) + 16 * g;
        size_t b0 = ((((size_t)kstep * 2 + 0) * 8 + tile) * 64 + lane) * 8 + j;
        size_t b1 = ((((size_t)kstep * 2 + 1) * 8 + tile) * 64 + lane) * 8 + j;
        whl[b0] = hi;
        whl[b1] = lo;
    } else {
        __shared__ int h[NB];
        int w = blockIdx.x - 256, t = threadIdx.x;
        for (int i = t; i < NB; i += 256) h[i] = 0;
        __syncthreads();
        int base = w * EPW;
        for (int i = t; i < EPW; i += 256) atomicAdd(&h[dst[base + i] >> 8], 1);
        __syncthreads();
        for (int i = t; i < NB; i += 256) hist[i * NW + w] = h[i];
    }
}

// pass B: per-bucket exclusive scan across WGs (relative) + bucket totals
__global__ __launch_bounds__(256) void kbB2(const int* __restrict__ hist,
                                            int* __restrict__ off,
                                            int* __restrict__ btot) {
    __shared__ int s[NW];
    int b = blockIdx.x, t = threadIdx.x;
    int v = hist[b * NW + t];
    s[t] = v;
    __syncthreads();
    for (int o = 1; o < NW; o <<= 1) {
        int a = (t >= o) ? s[t - o] : 0;
        __syncthreads();
        s[t] += a;
        __syncthreads();
    }
    off[b * NW + t] = s[t] - v;
    if (t == NW - 1) btot[b] = s[t];
}

// bucket-base exclusive scan (one block)
__global__ __launch_bounds__(512) void kbT(const int* __restrict__ btot,
                                           int* __restrict__ bbase,
                                           int* __restrict__ rowptr) {
    __shared__ int s[512];
    int t = threadIdx.x;
    int v = (t < NB) ? btot[t] : 0;
    s[t] = v;
    __syncthreads();
    for (int o = 1; o < 512; o <<= 1) {
        int a = (t >= o) ? s[t - o] : 0;
        __syncthreads();
        s[t] += a;
        __syncthreads();
    }
    if (t < NB) bbase[t] = s[t] - v;
    if (t == NB - 1) { bbase[NB] = s[t]; rowptr[NNODES] = NEDGES; }
}

// FUSED interleaved: every 7th block (b%7==0, b/7<256) is a kbC2 scatter block;
// the rest run gemm1 <FIN,2,1>. Spreads scatter across the dispatch for overlap.
__global__ __launch_bounds__(256) void k_c2g1(const int* __restrict__ src,
                                              const int* __restrict__ dst,
                                              const int* __restrict__ off,
                                              const int* __restrict__ bbase,
                                              int* __restrict__ pairs,
                                              const float* __restrict__ x,
                                              const unsigned short* __restrict__ whl1,
                                              void* __restrict__ hwbv) {
    int b = blockIdx.x;
    if ((b % 7 == 0) && (b / 7 < 256)) {
        __shared__ int cur[NB];
        int w = b / 7, t = threadIdx.x;
        for (int i = t; i < NB; i += 256) cur[i] = off[i * NW + w] + bbase[i];
        __syncthreads();
        int base = w * EPW;
        for (int i = t; i < EPW; i += 256) {
            int d = dst[base + i];
            int pos = atomicAdd(&cur[d >> 8], 1);
            pairs[pos] = (src[base + i] << 8) | (d & 255);
        }
    } else {
        int sbefore = (b + 6) / 7; if (sbefore > 256) sbefore = 256;
        gemm_body<FIN, 2, 1>(b - sbefore, x, whl1, hwbv);
    }
}

// per bucket: count per node (LDS), local scan -> rowptr/dis/selfn
__global__ __launch_bounds__(256) void kb2y(const int* __restrict__ bbase,
                                            const int* __restrict__ pairs,
                                            int* __restrict__ rowptr,
                                            float* __restrict__ dis,
                                            float* __restrict__ selfn) {
    int b = blockIdx.x;
    int nbase = b * 256;
    int nmax = NNODES - nbase; if (nmax > 256) nmax = 256;
    __shared__ int cnt[256];
    __shared__ int cur[256];
    int t = threadIdx.x;
    cnt[t] = 0;
    __syncthreads();
    int beg = bbase[b], end = bbase[b + 1];
    for (int i = beg + t; i < end; i += 256) atomicAdd(&cnt[pairs[i] & 255], 1);
    __syncthreads();
    int v = cnt[t];
    cur[t] = v;
    __syncthreads();
    for (int o = 1; o < 256; o <<= 1) {
        int a = (t >= o) ? cur[t - o] : 0;
        __syncthreads();
        cur[t] += a;
        __syncthreads();
    }
    if (t < nmax) {
        rowptr[nbase + t] = cur[t] - v + beg;
        float d = 1.0f + (float)v;
        dis[nbase + t] = rsqrtf(d);
        selfn[nbase + t] = 1.0f / d;
    }
}

// per bucket: place pairs directly as packed edges (src<<15 | u15 weight)
__global__ __launch_bounds__(256) void kb2z(const int* __restrict__ bbase,
                                            const int* __restrict__ pairs,
                                            const int* __restrict__ rowptr,
                                            const float* __restrict__ dis,
                                            unsigned int* __restrict__ edgp) {
    int b = blockIdx.x;
    int nbase = b * 256;
    int nmax = NNODES - nbase; if (nmax > 256) nmax = 256;
    __shared__ int cur[256];
    __shared__ float disl[256];
    int t = threadIdx.x;
    if (t < nmax) {
        cur[t] = rowptr[nbase + t];
        disl[t] = dis[nbase + t];
    }
    __syncthreads();
    int beg = bbase[b], end = bbase[b + 1];
    for (int i = beg + t; i < end; i += 256) {
        int p = pairs[i];
        int s = p >> 8;
        float w = dis[s] * disl[p & 255];
        unsigned int u = (unsigned int)(w * 32767.f + 0.5f);
        int pos = atomicAdd(&cur[p & 255], 1);
        edgp[pos] = ((unsigned int)s << 15) | u;
    }
}

// standalone GEMM for layers 2/3
template<int K, int MODE, int OUT8>
__global__ __launch_bounds__(256) void k_gemm_mfma(const void* __restrict__ Araw,
                                                   const unsigned short* __restrict__ whl,
                                                   void* __restrict__ hwbv) {
    gemm_body<K, MODE, OUT8>(blockIdx.x, Araw, whl, hwbv);
}

// SUBWAVE-PER-NODE gather: 16-lane subwave owns one node. fp8: 8 edges/iter;
// bf16: 4 edges/iter. Self-term inline from hwb[node]*selfn + bias.
template<int IN8>
__global__ __launch_bounds__(256) void k_gather(const int* __restrict__ rowptr,
                                                const unsigned int* __restrict__ edgp,
                                                const void* __restrict__ hwbv,
                                                const float* __restrict__ selfn,
                                                const float* __restrict__ bias,
                                                unsigned short* __restrict__ agb) {
    const int lane = threadIdx.x & 63;
    const int sub = lane >> 4;
    const int l4 = lane & 15;
    const int node = blockIdx.x * 16 + ((threadIdx.x >> 6) << 2) + sub;
    int beg = rowptr[node], end = rowptr[node + 1];
    const float q = IN8 ? (1.0f / (32767.0f * 64.0f)) : (1.0f / 32767.0f);
    const unsigned char* hb = (const unsigned char*)hwbv;
    f32x2 a0 = {0.f,0.f}, a1 = {0.f,0.f}, a2 = {0.f,0.f}, a3 = {0.f,0.f};
    int e = beg;
    if (IN8) {
        for (; e + 7 < end; e += 8) {
            unsigned int p0 = edgp[e], p1 = edgp[e + 1];
            unsigned int p2 = edgp[e + 2], p3 = edgp[e + 3];
            unsigned int p4 = edgp[e + 4], p5 = edgp[e + 5];
            unsigned int p6 = edgp[e + 6], p7 = edgp[e + 7];
            uint2 v0 = *(const uint2*)(hb + (size_t)(p0 >> 15) * HID + l4 * 8);
            uint2 v1 = *(const uint2*)(hb + (size_t)(p1 >> 15) * HID + l4 * 8);
            uint2 v2 = *(const uint2*)(hb + (size_t)(p2 >> 15) * HID + l4 * 8);
            uint2 v3 = *(const uint2*)(hb + (size_t)(p3 >> 15) * HID + l4 * 8);
            uint2 v4 = *(const uint2*)(hb + (size_t)(p4 >> 15) * HID + l4 * 8);
            uint2 v5 = *(const uint2*)(hb + (size_t)(p5 >> 15) * HID + l4 * 8);
            uint2 v6 = *(const uint2*)(hb + (size_t)(p6 >> 15) * HID + l4 * 8);
            uint2 v7 = *(const uint2*)(hb + (size_t)(p7 >> 15) * HID + l4 * 8);
            float w0 = (float)(p0 & 0x7fffu) * q, w1 = (float)(p1 & 0x7fffu) * q;
            float w2 = (float)(p2 & 0x7fffu) * q, w3 = (float)(p3 & 0x7fffu) * q;
            float w4 = (float)(p4 & 0x7fffu) * q, w5 = (float)(p5 & 0x7fffu) * q;
            float w6 = (float)(p6 & 0x7fffu) * q, w7 = (float)(p7 & 0x7fffu) * q;
            f32x2 wa = {w0, w0}, wb = {w1, w1}, wc = {w2, w2}, wd = {w3, w3};
            f32x2 we = {w4, w4}, wf = {w5, w5}, wg = {w6, w6}, wh = {w7, w7};
            a0 += e8plo(v0.x) * wa; a1 += e8phi(v0.x) * wa;
            a2 += e8plo(v0.y) * wa; a3 += e8phi(v0.y) * wa;
            a0 += e8plo(v1.x) * wb; a1 += e8phi(v1.x) * wb;
            a2 += e8plo(v1.y) * wb; a3 += e8phi(v1.y) * wb;
            a0 += e8plo(v2.x) * wc; a1 += e8phi(v2.x) * wc;
            a2 += e8plo(v2.y) * wc; a3 += e8phi(v2.y) * wc;
            a0 += e8plo(v3.x) * wd; a1 += e8phi(v3.x) * wd;
            a2 += e8plo(v3.y) * wd; a3 += e8phi(v3.y) * wd;
            a0 += e8plo(v4.x) * we; a1 += e8phi(v4.x) * we;
            a2 += e8plo(v4.y) * we; a3 += e8phi(v4.y) * we;
            a0 += e8plo(v5.x) * wf; a1 += e8phi(v5.x) * wf;
            a2 += e8plo(v5.y) * wf; a3 += e8phi(v5.y) * wf;
            a0 += e8plo(v6.x) * wg; a1 += e8phi(v6.x) * wg;
            a2 += e8plo(v6.y) * wg; a3 += e8phi(v6.y) * wg;
            a0 += e8plo(v7.x) * wh; a1 += e8phi(v7.x) * wh;
            a2 += e8plo(v7.y) * wh; a3 += e8phi(v7.y) * wh;
        }
    } else {
        for (; e + 3 < end; e += 4) {
            unsigned int p0 = edgp[e], p1 = edgp[e + 1];
            unsigned int p2 = edgp[e + 2], p3 = edgp[e + 3];
            float w0 = (float)(p0 & 0x7fffu) * q;
            float w1 = (float)(p1 & 0x7fffu) * q;
            float w2 = (float)(p2 & 0x7fffu) * q;
            float w3 = (float)(p3 & 0x7fffu) * q;
            f32x2 wa = {w0, w0}, wb = {w1, w1}, wc = {w2, w2}, wd = {w3, w3};
            size_t r0 = (size_t)(p0 >> 15), r1 = (size_t)(p1 >> 15);
            size_t r2 = (size_t)(p2 >> 15), r3 = (size_t)(p3 >> 15);
            uint4 v0 = *(const uint4*)(hb + r0 * (HID * 2) + l4 * 16);
            uint4 v1 = *(const uint4*)(hb + r1 * (HID * 2) + l4 * 16);
            uint4 v2 = *(const uint4*)(hb + r2 * (HID * 2) + l4 * 16);
            uint4 v3 = *(const uint4*)(hb + r3 * (HID * 2) + l4 * 16);
            a0 += bdec(v0.x) * wa; a1 += bdec(v0.y) * wa;
            a2 += bdec(v0.z) * wa; a3 += bdec(v0.w) * wa;
            a0 += bdec(v1.x) * wb; a1 += bdec(v1.y) * wb;
            a2 += bdec(v1.z) * wb; a3 += bdec(v1.w) * wb;
            a0 += bdec(v2.x) * wc; a1 += bdec(v2.y) * wc;
            a2 += bdec(v2.z) * wc; a3 += bdec(v2.w) * wc;
            a0 += bdec(v3.x) * wd; a1 += bdec(v3.y) * wd;
            a2 += bdec(v3.z) * wd; a3 += bdec(v3.w) * wd;
        }
    }
    for (; e < end; ++e) {
        unsigned int p = edgp[e];
        float w = (float)(p & 0x7fffu) * q;
        f32x2 wa = {w, w};
        size_t r = (size_t)(p >> 15);
        if (IN8) {
            uint2 v = *(const uint2*)(hb + r * HID + l4 * 8);
            a0 += e8plo(v.x) * wa; a1 += e8phi(v.x) * wa;
            a2 += e8plo(v.y) * wa; a3 += e8phi(v.y) * wa;
        } else {
            uint4 v = *(const uint4*)(hb + r * (HID * 2) + l4 * 16);
            a0 += bdec(v.x) * wa; a1 += bdec(v.y) * wa;
            a2 += bdec(v.z) * wa; a3 += bdec(v.w) * wa;
        }
    }
    // self-term: hw[node] * selfn + bias, relu, store bf16
    float sn = selfn[node] * (IN8 ? (1.0f / 64.0f) : 1.0f);
    f32x2 sn2 = {sn, sn};
    f32x2 h0, h1, h2, h3;
    if (IN8) {
        uint2 v = *(const uint2*)(hb + (size_t)node * HID + l4 * 8);
        h0 = e8plo(v.x); h1 = e8phi(v.x); h2 = e8plo(v.y); h3 = e8phi(v.y);
    } else {
        uint4 v = *(const uint4*)(hb + (size_t)node * (HID * 2) + l4 * 16);
        h0 = bdec(v.x); h1 = bdec(v.y); h2 = bdec(v.z); h3 = bdec(v.w);
    }
    float4 bA = *(const float4*)&bias[l4 * 8];
    float4 bB = *(const float4*)&bias[l4 * 8 + 4];
    a0 += h0 * sn2; a1 += h1 * sn2; a2 += h2 * sn2; a3 += h3 * sn2;
    float r0 = fmaxf(a0[0] + bA.x, 0.f), r1 = fmaxf(a0[1] + bA.y, 0.f);
    float r2 = fmaxf(a1[0] + bA.z, 0.f), r3 = fmaxf(a1[1] + bA.w, 0.f);
    float r4 = fmaxf(a2[0] + bB.x, 0.f), r5 = fmaxf(a2[1] + bB.y, 0.f);
    float r6 = fmaxf(a3[0] + bB.z, 0.f), r7 = fmaxf(a3[1] + bB.w, 0.f);
    uint4 o;
    o.x = (unsigned int)f2b(r0) | ((unsigned int)f2b(r1) << 16);
    o.y = (unsigned int)f2b(r2) | ((unsigned int)f2b(r3) << 16);
    o.z = (unsigned int)f2b(r4) | ((unsigned int)f2b(r5) << 16);
    o.w = (unsigned int)f2b(r6) | ((unsigned int)f2b(r7) << 16);
    *(uint4*)(agb + (size_t)node * HID + l4 * 8) = o;
}

// fused pool + BN + head. One graph per block, 1024 threads.
__global__ __launch_bounds__(1024) void k_pool_bn_head(const unsigned short* __restrict__ h,
                                                       const int* __restrict__ batch,
                                                       const float* __restrict__ gamma,
                                                       const float* __restrict__ beta,
                                                       const float* __restrict__ mean,
                                                       const float* __restrict__ var,
                                                       const float* __restrict__ lw,
                                                       const float* __restrict__ lb,
                                                       float* __restrict__ xb,
                                                       float* __restrict__ out2) {
    int g = blockIdx.x;
    int tid = threadIdx.x;
    int fg = tid & 15;
    int r = tid >> 4;
    __shared__ int bounds[2];
    if (tid < 2) {
        int target = g + tid;
        int a = 0, b = NNODES;
        while (a < b) { int m = (a + b) >> 1; if (batch[m] < target) a = m + 1; else b = m; }
        bounds[tid] = a;
    }
    __syncthreads();
    int s1 = bounds[0], e1 = bounds[1];
    f32x2 acc[4] = {};
    for (int i = s1 + r; i < e1; i += 64) {
        uint4 v = *(const uint4*)(h + (size_t)i * HID + fg * 8);
        acc[0] += bdec(v.x); acc[1] += bdec(v.y); acc[2] += bdec(v.z); acc[3] += bdec(v.w);
    }
    __shared__ f32x2 red[64][16][4];   // 32KB
    #pragma unroll
    for (int j = 0; j < 4; ++j) red[r][fg][j] = acc[j];
    __syncthreads();
    for (int off = 32; off >= 1; off >>= 1) {
        if (r < off) {
            #pragma unroll
            for (int j = 0; j < 4; ++j) red[r][fg][j] += red[r + off][fg][j];
        }
        __syncthreads();
    }
    __shared__ float xbl[128];
    if (r == 0) {
        float cnt = (float)((e1 - s1) > 0 ? (e1 - s1) : 1);
        float inv = 1.0f / cnt;
        #pragma unroll
        for (int j = 0; j < 4; ++j) {
            #pragma unroll
            for (int k2 = 0; k2 < 2; ++k2) {
                int f = fg * 8 + j * 2 + k2;
                float pooled = red[0][fg][j][k2] * inv;
                float xbv = (pooled - mean[f]) * rsqrtf(var[f] + BN_EPS_C) * gamma[f] + beta[f];
                xb[g * HID + f] = xbv;
                xbl[f] = xbv;
            }
        }
    }
    __syncthreads();
    if (tid < 64) {
        float x0 = xbl[tid], x1 = xbl[tid + 64];
        float s0 = x0 * lw[tid * 2 + 0] + x1 * lw[(tid + 64) * 2 + 0];
        float s1h = x0 * lw[tid * 2 + 1] + x1 * lw[(tid + 64) * 2 + 1];
        #pragma unroll
        for (int o = 1; o < 64; o <<= 1) {
            s0 += __shfl_xor(s0, o);
            s1h += __shfl_xor(s1h, o);
        }
        if (tid == 0) {
            out2[g * 2 + 0] = fmaxf(s0 + lb[0], 0.f);
            out2[g * 2 + 1] = fmaxf(s1h + lb[1], 0.f);
        }
    }
}

extern "C" void kernel_launch(void* const* d_in, const int* in_sizes, int n_in,
                              void* d_out, int out_size, void* d_ws, size_t ws_size,
                              hipStream_t stream) {
    const float* x     = (const float*)d_in[0];
    const int*   ei    = (const int*)d_in[1];
    const int*   batch = (const int*)d_in[3];
    const float* W1 = (const float*)d_in[4];
    const float* b1 = (const float*)d_in[5];
    const float* W2 = (const float*)d_in[6];
    const float* b2 = (const float*)d_in[7];
    const float* W3 = (const float*)d_in[8];
    const float* b3 = (const float*)d_in[9];
    const float* gamma = (const float*)d_in[10];
    const float* beta  = (const float*)d_in[11];
    const float* mean  = (const float*)d_in[12];
    const float* var   = (const float*)d_in[13];
    const float* lw = (const float*)d_in[14];
    const float* lb = (const float*)d_in[15];
    float* out = (float*)d_out;

    char* p = (char*)d_ws;
    unsigned short* HWB = (unsigned short*)p;          p += (size_t)NNODES * HID * 2;  // 25.6MB (fp8 uses half)
    unsigned short* AGB = (unsigned short*)p;          p += (size_t)NNODES * HID * 2;  // 25.6MB
    float* DIS    = (float*)p;                         p += (size_t)NNODES * 4;
    float* SELFN  = (float*)p;                         p += (size_t)NNODES * 4;
    int*   ROWPTR = (int*)p;                           p += (size_t)(NNODES + 64) * 4;
    unsigned int* EDGP = (unsigned int*)p;             p += (size_t)NEDGES * 4;
    int*   PAIRS  = (int*)p;                           p += (size_t)NEDGES * 4;   // dedicated (gemm1 overlaps kbC2)
    int*   BTOT   = (int*)p;                           p += 512 * 4;
    int*   BBASE  = (int*)p;                           p += 512 * 4;
    unsigned short* WHL1 = (unsigned short*)p;         p += (size_t)FIN * 128 * 2 * 2;
    unsigned short* WHL2 = (unsigned short*)p;         p += (size_t)HID * 128 * 2 * 2;
    unsigned short* WHL3 = (unsigned short*)p;
    // build-phase aliases (consumed before gather1 writes AGB)
    int*   HIST   = (int*)AGB;                         // NB*NW i (400KB)
    int*   OFF    = HIST + NB * NW;                    // NB*NW i

    const int* srcv = ei;
    const int* dstv = ei + NEDGES;

    // ---- build + layer-1 pipeline with independent-kernel fusion ----
    k_prep<<<512, 256, 0, stream>>>(W1, W2, W3, WHL1, WHL2, WHL3, dstv, HIST);
    kbB2<<<NB, 256, 0, stream>>>(HIST, OFF, BTOT);
    kbT<<<1, 512, 0, stream>>>(BTOT, BBASE, ROWPTR);
    // kbC2 scatter (interleaved every 7th block) || gemm1 (bf16(x) @ W1hi -> fp8 HWB)
    k_c2g1<<<256 + GEMM_BLKS, 256, 0, stream>>>(srcv, dstv, OFF, BBASE, PAIRS, x, WHL1, HWB);
    kb2y<<<NB, 256, 0, stream>>>(BBASE, PAIRS, ROWPTR, DIS, SELFN);
    kb2z<<<NB, 256, 0, stream>>>(BBASE, PAIRS, ROWPTR, DIS, EDGP);

    const int ggat = NNODES / 16;   // 6250, exact
    dim3 gg(GEMM_BLKS);

    k_gather<1><<<ggat, 256, 0, stream>>>(ROWPTR, EDGP, HWB, SELFN, b1, AGB);
    // layer 2 (A = relu'd bf16 AGB; hwb fp8)
    k_gemm_mfma<HID, 1, 1><<<gg, 256, 0, stream>>>(AGB, WHL2, HWB);
    k_gather<1><<<ggat, 256, 0, stream>>>(ROWPTR, EDGP, HWB, SELFN, b2, AGB);
    // layer 3 (hwb bf16 -- last layer's quantization is undamped, keep precise)
    k_gemm_mfma<HID, 1, 0><<<gg, 256, 0, stream>>>(AGB, WHL3, HWB);
    k_gather<0><<<ggat, 256, 0, stream>>>(ROWPTR, EDGP, HWB, SELFN, b3, AGB);

    // fused pool + BN + head
    k_pool_bn_head<<<NG, 1024, 0, stream>>>(AGB, batch, gamma, beta, mean, var,
                                            lw, lb, out, out + (size_t)NG * HID);
}